// Round 13
// baseline (399.852 us; speedup 1.0000x reference)
//
#include <hip/hip_runtime.h>
#include <hip/hip_bf16.h>

// GCN, bf16 node features + fp32 accumulation.
//  CSR = u32 src only (coef factored: tmp = sum xval*dinv[src], then *dinv[dst]).
//  Padding sentinel src=N with dinv[N]=0 -> no csr pre-zero needed.
//  count: 8 XCD-pinned partition counters; scan3 -> offs + per-partition bases
//  + pad fill. k_mm1_scatter fuses layer-1 GEMM with the atomic-free scatter.
//  3x k_agg (uniform 8-batches, fused next-W GEMM); k_pool.

typedef unsigned short u16;
typedef unsigned int u32;

__device__ __forceinline__ float bf2f(u32 u) {
  return __uint_as_float(u << 16);
}
__device__ __forceinline__ u16 f2bf(float f) {
  u32 x = __float_as_uint(f);
  return (u16)((x + 0x7fffu + ((x >> 16) & 1u)) >> 16);  // RNE
}

// ---------------- init: zero the 8 partition counters ----------------
__global__ __launch_bounds__(256) void k_init(int* __restrict__ cnt8, int n8) {
  int i = blockIdx.x * blockDim.x + threadIdx.x;
  int stride = gridDim.x * blockDim.x;
  for (; i < n8; i += stride) cnt8[i] = 0;
}

// count in-degree into partition (blockIdx&7) counter; rank = atomic return.
__global__ __launch_bounds__(256) void k_count_rank(const int* __restrict__ dst, int* __restrict__ cnt8,
                                                    int* __restrict__ rank, int e_count, int n) {
  int e = blockIdx.x * blockDim.x + threadIdx.x;
  if (e < e_count) {
    int p = blockIdx.x & 7;
    rank[e] = atomicAdd(&cnt8[p * n + dst[e]], 1);
  }
}

// scan over PADDED totals ((sum8+7)&~7)
__global__ __launch_bounds__(256) void k_scan1(const int* __restrict__ cnt8, int n, int* __restrict__ bsum) {
  __shared__ int s[256];
  int b = blockIdx.x, t = threadIdx.x;
  int base = b * 1024;
  int sum = 0;
  #pragma unroll
  for (int i = 0; i < 4; ++i) {
    int idx = base + t + i * 256;
    if (idx < n) {
      int c = 0;
      #pragma unroll
      for (int q = 0; q < 8; ++q) c += cnt8[q * n + idx];
      sum += (c + 7) & ~7;
    }
  }
  s[t] = sum; __syncthreads();
  for (int off = 128; off > 0; off >>= 1) {
    if (t < off) s[t] += s[t + off];
    __syncthreads();
  }
  if (t == 0) bsum[b] = s[0];
}

__global__ __launch_bounds__(128) void k_scan2(int* __restrict__ bsum, int nb, int* __restrict__ total_out) {
  __shared__ int sh[128];
  int t = threadIdx.x;
  sh[t] = (t < nb) ? bsum[t] : 0;
  __syncthreads();
  for (int off = 1; off < 128; off <<= 1) {
    int x = sh[t];
    int y = (t >= off) ? sh[t - off] : 0;
    __syncthreads();
    sh[t] = x + y;
    __syncthreads();
  }
  if (t < nb) bsum[t] = (t == 0) ? 0 : sh[t - 1];
  if (t == 0) *total_out = sh[127];
}

// scan3: padded offsets, dinv (real counts), per-partition scatter bases
// (overwrites cnt8 in place), sentinel pad fill, dinv[n]=0.
__global__ __launch_bounds__(256) void k_scan3(int* __restrict__ cnt8, int n,
                                               const int* __restrict__ bsum_ex, int* __restrict__ offsets,
                                               float* __restrict__ dinv, u32* __restrict__ csr) {
  __shared__ int sh[256];
  int b = blockIdx.x, t = threadIdx.x;
  int base = b * 1024 + t * 4;
  int cq[4][8];
  int c[4], v[4];
  #pragma unroll
  for (int i = 0; i < 4; ++i) {
    c[i] = 0;
    #pragma unroll
    for (int q = 0; q < 8; ++q) {
      int x = (base + i < n) ? cnt8[q * n + base + i] : 0;
      cq[i][q] = x;
      c[i] += x;
    }
    v[i] = (c[i] + 7) & ~7;
    if (base + i < n) dinv[base + i] = rsqrtf((float)c[i] + 1.0f);
  }
  sh[t] = v[0] + v[1] + v[2] + v[3];
  __syncthreads();
  for (int off = 1; off < 256; off <<= 1) {
    int x = sh[t];
    int y = (t >= off) ? sh[t - off] : 0;
    __syncthreads();
    sh[t] = x + y;
    __syncthreads();
  }
  int run = bsum_ex[b] + ((t == 0) ? 0 : sh[t - 1]);
  #pragma unroll
  for (int i = 0; i < 4; ++i) {
    if (base + i < n) {
      offsets[base + i] = run;
      int pb = run;
      #pragma unroll
      for (int q = 0; q < 8; ++q) {
        cnt8[q * n + base + i] = pb;  // partition base (in-place)
        pb += cq[i][q];
      }
      for (int j = run + c[i]; j < run + v[i]; ++j) csr[j] = (u32)n;  // sentinel pads
      run += v[i];
    }
  }
  if (b == 0 && t == 0) dinv[n] = 0.f;  // sentinel: coef contribution = 0
}

// ---------------- fused layer-1 GEMM (blocks [0,mmb)) + scatter (rest) ----------------
__global__ __launch_bounds__(256, 4) void k_mm1_scatter(
    const int* __restrict__ ids, const float* __restrict__ emb,
    const float* __restrict__ W1, u16* __restrict__ out, int n, int mmb,
    const int* __restrict__ src, const int* __restrict__ dst,
    const int* __restrict__ rank, const int* __restrict__ pbase,
    u32* __restrict__ csr, int e_count) {
  if ((int)blockIdx.x >= mmb) {
    int eb = blockIdx.x - mmb;
    int e = eb * 256 + threadIdx.x;
    if (e < e_count) {
      int p = eb & 7;  // matches k_count_rank's blockIdx&7
      int d = dst[e];
      int pos = pbase[p * n + d] + rank[e];
      __builtin_nontemporal_store((u32)src[e], &csr[pos]);
    }
    return;
  }

  const int lane = threadIdx.x & 63;
  const int w = threadIdx.x >> 6;
  const int r = blockIdx.x * 256 + w * 64 + lane;
  const int rid = ids[(r < n) ? r : (n - 1)];
  const float4* __restrict__ xrow = reinterpret_cast<const float4*>(emb + (size_t)rid * 128);

  float acc[64];
  #pragma unroll
  for (int j = 0; j < 64; ++j) acc[j] = 0.f;

  #pragma unroll 1
  for (int s = 0; s < 4; ++s) {
    float4 xb[8];
    #pragma unroll
    for (int i = 0; i < 8; ++i) xb[i] = xrow[s * 8 + i];
    const float* __restrict__ wbase = W1 + (size_t)(s * 32) * 64;
    #pragma unroll
    for (int i = 0; i < 8; ++i) {
      const float* __restrict__ w0 = wbase + (i * 4) * 64;
      #pragma unroll
      for (int j = 0; j < 64; ++j) {
        acc[j] = fmaf(xb[i].x, w0[j], acc[j]);
        acc[j] = fmaf(xb[i].y, w0[64 + j], acc[j]);
        acc[j] = fmaf(xb[i].z, w0[128 + j], acc[j]);
        acc[j] = fmaf(xb[i].w, w0[192 + j], acc[j]);
      }
    }
  }

  if (r < n) {
    u16* op = out + (size_t)r * 64;
    #pragma unroll
    for (int q = 0; q < 8; ++q) {
      uint2 pk;
      pk.x = ((u32)f2bf(acc[q * 4 + 1]) << 16) | f2bf(acc[q * 4 + 0]);
      pk.y = ((u32)f2bf(acc[q * 4 + 3]) << 16) | f2bf(acc[q * 4 + 2]);
      *reinterpret_cast<uint2*>(op + q * 4) = pk;
    }
  }
}

// ---------------- fused aggregation + next-layer GEMM ----------------
// csr = u32 src. Per 8-batch (one node, thanks to padding):
// tmp = sum xval * dinv[src]  (dinv load is uniform -> scalar pipe), then
// acc_node = fma(tmp, dinv[node], acc_node). Sentinel src=n has dinv=0.

template <bool FINAL>
__global__ __launch_bounds__(256) void k_agg(const u16* __restrict__ xw, const u32* __restrict__ csr,
                                             const int* __restrict__ offs, const float* __restrict__ dinv,
                                             const float* __restrict__ bias, const float* __restrict__ Wn,
                                             u16* __restrict__ out, int n) {
  const int lane = threadIdx.x & 63;
  const int w = threadIdx.x >> 6;
  const float bl = bias[lane];
  const int ngroups = (n + 3) >> 2;
  const int nwaves = gridDim.x * 4;

  for (int grp = blockIdx.x * 4 + w; grp < ngroups; grp += nwaves) {
    const int v0 = grp * 4;
    const int c1 = (v0 + 1 < n) ? v0 + 1 : n;
    const int c2 = (v0 + 2 < n) ? v0 + 2 : n;
    const int c3 = (v0 + 3 < n) ? v0 + 3 : n;
    const int b0 = offs[v0], b1 = offs[c1], b2 = offs[c2], b3 = offs[c3];
    const int b4 = offs[(v0 + 4 < n) ? v0 + 4 : n];

    const float d0 = dinv[v0];
    const float d1 = dinv[(c1 < n) ? c1 : v0];
    const float d2 = dinv[(c2 < n) ? c2 : v0];
    const float d3 = dinv[(c3 < n) ? c3 : v0];
    float acc0 = fmaf(bf2f((u32)xw[(size_t)v0 * 64 + lane]), d0 * d0, bl);
    float acc1 = (c1 < n) ? fmaf(bf2f((u32)xw[(size_t)c1 * 64 + lane]), d1 * d1, bl) : 0.f;
    float acc2 = (c2 < n) ? fmaf(bf2f((u32)xw[(size_t)c2 * 64 + lane]), d2 * d2, bl) : 0.f;
    float acc3 = (c3 < n) ? fmaf(bf2f((u32)xw[(size_t)c3 * 64 + lane]), d3 * d3, bl) : 0.f;

    int e = b0;
    while (e < b4) {
      int cc = b4 - e;
      cc = (cc < 64) ? cc : 64;
      u32 ce = (u32)n;
      if (lane < cc) ce = csr[e + lane];
      // uniform 8-edge batches; each batch maps to exactly one node
      for (int bs = 0; bs < cc; bs += 8) {
        float xv[8], dv[8];
        #pragma unroll
        for (int t = 0; t < 8; ++t) {
          int sb = __builtin_amdgcn_readlane((int)ce, bs + t);
          xv[t] = bf2f((u32)xw[(size_t)sb * 64 + lane]);
          dv[t] = dinv[sb];
        }
        float tmp = 0.f;
        #pragma unroll
        for (int t = 0; t < 8; ++t) tmp = fmaf(xv[t], dv[t], tmp);
        const int ep = e + bs;  // wave-uniform
        if (ep < b1) acc0 = fmaf(tmp, d0, acc0);
        else if (ep < b2) acc1 = fmaf(tmp, d1, acc1);
        else if (ep < b3) acc2 = fmaf(tmp, d2, acc2);
        else acc3 = fmaf(tmp, d3, acc3);
      }
      e += cc;
    }

    float h0 = fmaxf(acc0, 0.f), h1 = fmaxf(acc1, 0.f);
    float h2 = fmaxf(acc2, 0.f), h3 = fmaxf(acc3, 0.f);
    if constexpr (FINAL) {
      out[(size_t)v0 * 64 + lane] = f2bf(h0);
      if (c1 < n) out[(size_t)c1 * 64 + lane] = f2bf(h1);
      if (c2 < n) out[(size_t)c2 * 64 + lane] = f2bf(h2);
      if (c3 < n) out[(size_t)c3 * 64 + lane] = f2bf(h3);
    } else {
      const int hb0 = __float_as_int(h0), hb1 = __float_as_int(h1);
      const int hb2 = __float_as_int(h2), hb3 = __float_as_int(h3);
      float o0 = 0.f, o1 = 0.f, o2 = 0.f, o3 = 0.f;
      #pragma unroll
      for (int k = 0; k < 64; ++k) {
        float wk = Wn[k * 64 + lane];
        o0 = fmaf(__int_as_float(__builtin_amdgcn_readlane(hb0, k)), wk, o0);
        o1 = fmaf(__int_as_float(__builtin_amdgcn_readlane(hb1, k)), wk, o1);
        o2 = fmaf(__int_as_float(__builtin_amdgcn_readlane(hb2, k)), wk, o2);
        o3 = fmaf(__int_as_float(__builtin_amdgcn_readlane(hb3, k)), wk, o3);
      }
      out[(size_t)v0 * 64 + lane] = f2bf(o0);
      if (c1 < n) out[(size_t)c1 * 64 + lane] = f2bf(o1);
      if (c2 < n) out[(size_t)c2 * 64 + lane] = f2bf(o2);
      if (c3 < n) out[(size_t)c3 * 64 + lane] = f2bf(o3);
    }
  }
}

// ---------------- pooling + MLP head + sigmoid ----------------
__global__ __launch_bounds__(256) void k_pool(const u16* __restrict__ x, const int* __restrict__ batch, int n,
                                              const float* __restrict__ Wf1, const float* __restrict__ bf1,
                                              const float* __restrict__ Wf2, const float* __restrict__ bf2,
                                              float* __restrict__ out) {
  int g = blockIdx.x;
  int tid = threadIdx.x, lane = tid & 63, w = tid >> 6;
  int a = 0, b = n;
  while (a < b) { int m = (a + b) >> 1; if (batch[m] < g) a = m + 1; else b = m; }
  int lo = a;
  b = n;
  while (a < b) { int m = (a + b) >> 1; if (batch[m] < g + 1) a = m + 1; else b = m; }
  int hi = a;

  float acc = 0.f;
  for (int r = lo + w; r < hi; r += 4) acc += bf2f((u32)x[(size_t)r * 64 + lane]);
  __shared__ float red[4][64];
  __shared__ float mean[64];
  red[w][lane] = acc;
  __syncthreads();
  if (w == 0) {
    float s = red[0][lane] + red[1][lane] + red[2][lane] + red[3][lane];
    mean[lane] = s / fmaxf((float)(hi - lo), 1.0f);
  }
  __syncthreads();
  if (w == 0) {
    float h = bf1[lane];
    #pragma unroll
    for (int k = 0; k < 64; ++k) h = fmaf(mean[k], Wf1[k * 64 + lane], h);
    h = fmaxf(h, 0.f);
    float vv = h * Wf2[lane];
    for (int off = 32; off > 0; off >>= 1) vv += __shfl_down(vv, off, 64);
    if (lane == 0) out[g] = 1.0f / (1.0f + expf(-(vv + bf2[0])));
  }
}

static inline char* align256(char* p) {
  return (char*)(((uintptr_t)p + 255) & ~(uintptr_t)255);
}

extern "C" void kernel_launch(void* const* d_in, const int* in_sizes, int n_in,
                              void* d_out, int out_size, void* d_ws, size_t ws_size,
                              hipStream_t stream) {
  const int*   x_ids = (const int*)d_in[0];
  const int*   edge  = (const int*)d_in[1];
  const int*   batch = (const int*)d_in[2];
  const float* emb   = (const float*)d_in[3];
  const float* W1    = (const float*)d_in[4];
  const float* b1    = (const float*)d_in[5];
  const float* W2    = (const float*)d_in[6];
  const float* b2    = (const float*)d_in[7];
  const float* W3    = (const float*)d_in[8];
  const float* b3    = (const float*)d_in[9];
  const float* Wf1   = (const float*)d_in[10];
  const float* bf1   = (const float*)d_in[11];
  const float* Wf2   = (const float*)d_in[12];
  const float* bf2   = (const float*)d_in[13];
  float* out = (float*)d_out;

  const int N = in_sizes[0];
  const int E = in_sizes[1] / 2;
  const int G = out_size;
  const int* e_src = edge;
  const int* e_dst = edge + E;

  const size_t EPAD = (size_t)E + 8 * (size_t)(N + 1) + 64;  // padded csr capacity

  // workspace layout (bf16 feature buffers, N+1 rows for sentinel)
  char* p = (char*)d_ws;
  u16*   bufA = (u16*)p;              p = align256(p + (size_t)(N + 1) * 64 * 2);
  u16*   bufB = (u16*)p;              p = align256(p + (size_t)(N + 1) * 64 * 2);
  u32*   csr  = (u32*)p;              p = align256(p + EPAD * 4);
  int*   rank = (int*)p;              p = align256(p + (size_t)E * 4);
  float* dinv = (float*)p;            p = align256(p + (size_t)(N + 1) * 4);
  int*   cnt8 = (int*)p;              p = align256(p + (size_t)8 * N * 4);
  int*   offs = (int*)p;              p = align256(p + (size_t)(N + 1) * 4);
  int*   bsum = (int*)p;              p = align256(p + (size_t)1024 * 4);
  (void)ws_size; (void)n_in;

  const int nb_scan = (N + 1023) / 1024;  // 98 for N=100000 (<=128)
  dim3 blk(256);

  // CSR build
  k_init<<<dim3(512), blk, 0, stream>>>(cnt8, 8 * N);
  k_count_rank<<<dim3((E + 255) / 256), blk, 0, stream>>>(e_dst, cnt8, rank, E, N);
  k_scan1<<<dim3(nb_scan), blk, 0, stream>>>(cnt8, N, bsum);
  k_scan2<<<dim3(1), dim3(128), 0, stream>>>(bsum, nb_scan, offs + N);
  k_scan3<<<dim3(nb_scan), blk, 0, stream>>>(cnt8, N, bsum, offs, dinv, csr);

  // fused: layer-1 GEMM (blocks [0,mmb)) overlapped with CSR scatter (rest)
  const int mmb = (N + 255) / 256;
  const int scb = (E + 255) / 256;
  k_mm1_scatter<<<dim3(mmb + scb), blk, 0, stream>>>(
      x_ids, emb, W1, bufA, N, mmb,
      e_src, e_dst, rank, cnt8, csr, E);

  // fused conv+next-GEMM chain (4 nodes/wave, grid-stride)
  k_agg<false><<<dim3(2048), blk, 0, stream>>>(bufA, csr, offs, dinv, b1, W2, bufB, N);
  k_agg<false><<<dim3(2048), blk, 0, stream>>>(bufB, csr, offs, dinv, b2, W3, bufA, N);
  k_agg<true><<<dim3(2048), blk, 0, stream>>>(bufA, csr, offs, dinv, b3, nullptr, bufB, N);

  // pool + MLP head
  k_pool<<<dim3(G), blk, 0, stream>>>(bufB, batch, N, Wf1, bf1, Wf2, bf2, out);
}

// Round 14
// 397.943 us; speedup vs baseline: 1.0048x; 1.0048x over previous
//
#include <hip/hip_runtime.h>
#include <hip/hip_bf16.h>
#include <hip/hip_fp8.h>

// GCN, fp8(e4m3) node features (scale S=256 folded into dinv) + fp32 accum.
//  CSR = u32 src only; padding sentinel src=N with dinv[N]=0, row N zeroed.
//  count: 8 XCD-pinned partition counters; atomic-free scatter fused with mm1.
//  3x k_agg (uniform 8-batches, fused next-W GEMM); k_pool.

typedef unsigned char u8;
typedef unsigned short u16;
typedef unsigned int u32;

#define FSCALE 256.0f
#define DINV_SCALE 0.0625f  /* 1/sqrt(FSCALE) */

__device__ __forceinline__ float fp8d(u32 b) {
#if __has_builtin(__builtin_amdgcn_cvt_f32_fp8)
  return __builtin_amdgcn_cvt_f32_fp8((int)b, 0);
#else
  __hip_fp8_e4m3 t; t.__x = (__hip_fp8_storage_t)b; return (float)t;
#endif
}
__device__ __forceinline__ u32 fp8e1(float f) {  // encode one (true value), pre-scaled by caller
#if __has_builtin(__builtin_amdgcn_cvt_pk_fp8_f32)
  return (u32)__builtin_amdgcn_cvt_pk_fp8_f32(f, 0.f, 0, false) & 0xffu;
#else
  __hip_fp8_e4m3 t(f); return (u32)t.__x;
#endif
}
__device__ __forceinline__ u32 fp8e4(float f0, float f1, float f2, float f3) {
#if __has_builtin(__builtin_amdgcn_cvt_pk_fp8_f32)
  int r = 0;
  r = __builtin_amdgcn_cvt_pk_fp8_f32(f0, f1, r, false);
  r = __builtin_amdgcn_cvt_pk_fp8_f32(f2, f3, r, true);
  return (u32)r;
#else
  __hip_fp8_e4m3 a(f0), b(f1), c(f2), d(f3);
  return (u32)a.__x | ((u32)b.__x << 8) | ((u32)c.__x << 16) | ((u32)d.__x << 24);
#endif
}

// ---------------- init: zero partition counters + sentinel feature rows ----------------
__global__ __launch_bounds__(256) void k_init(int* __restrict__ cnt8, int n8,
                                              u8* __restrict__ rowA, u8* __restrict__ rowB) {
  int i = blockIdx.x * blockDim.x + threadIdx.x;
  int stride = gridDim.x * blockDim.x;
  for (; i < n8; i += stride) cnt8[i] = 0;
  if (blockIdx.x == 0 && threadIdx.x < 64) {
    rowA[threadIdx.x] = 0;
    rowB[threadIdx.x] = 0;
  }
}

// count in-degree into partition (blockIdx&7) counter; rank = atomic return.
__global__ __launch_bounds__(256) void k_count_rank(const int* __restrict__ dst, int* __restrict__ cnt8,
                                                    int* __restrict__ rank, int e_count, int n) {
  int e = blockIdx.x * blockDim.x + threadIdx.x;
  if (e < e_count) {
    int p = blockIdx.x & 7;
    rank[e] = atomicAdd(&cnt8[p * n + dst[e]], 1);
  }
}

// scan over PADDED totals ((sum8+7)&~7)
__global__ __launch_bounds__(256) void k_scan1(const int* __restrict__ cnt8, int n, int* __restrict__ bsum) {
  __shared__ int s[256];
  int b = blockIdx.x, t = threadIdx.x;
  int base = b * 1024;
  int sum = 0;
  #pragma unroll
  for (int i = 0; i < 4; ++i) {
    int idx = base + t + i * 256;
    if (idx < n) {
      int c = 0;
      #pragma unroll
      for (int q = 0; q < 8; ++q) c += cnt8[q * n + idx];
      sum += (c + 7) & ~7;
    }
  }
  s[t] = sum; __syncthreads();
  for (int off = 128; off > 0; off >>= 1) {
    if (t < off) s[t] += s[t + off];
    __syncthreads();
  }
  if (t == 0) bsum[b] = s[0];
}

__global__ __launch_bounds__(128) void k_scan2(int* __restrict__ bsum, int nb, int* __restrict__ total_out) {
  __shared__ int sh[128];
  int t = threadIdx.x;
  sh[t] = (t < nb) ? bsum[t] : 0;
  __syncthreads();
  for (int off = 1; off < 128; off <<= 1) {
    int x = sh[t];
    int y = (t >= off) ? sh[t - off] : 0;
    __syncthreads();
    sh[t] = x + y;
    __syncthreads();
  }
  if (t < nb) bsum[t] = (t == 0) ? 0 : sh[t - 1];
  if (t == 0) *total_out = sh[127];
}

// scan3: padded offsets, dinv (scaled by 1/sqrt(S)), per-partition bases
// (overwrites cnt8 in place), sentinel pad fill, dinv[n]=0.
__global__ __launch_bounds__(256) void k_scan3(int* __restrict__ cnt8, int n,
                                               const int* __restrict__ bsum_ex, int* __restrict__ offsets,
                                               float* __restrict__ dinv, u32* __restrict__ csr) {
  __shared__ int sh[256];
  int b = blockIdx.x, t = threadIdx.x;
  int base = b * 1024 + t * 4;
  int cq[4][8];
  int c[4], v[4];
  #pragma unroll
  for (int i = 0; i < 4; ++i) {
    c[i] = 0;
    #pragma unroll
    for (int q = 0; q < 8; ++q) {
      int x = (base + i < n) ? cnt8[q * n + base + i] : 0;
      cq[i][q] = x;
      c[i] += x;
    }
    v[i] = (c[i] + 7) & ~7;
    if (base + i < n) dinv[base + i] = rsqrtf((float)c[i] + 1.0f) * DINV_SCALE;
  }
  sh[t] = v[0] + v[1] + v[2] + v[3];
  __syncthreads();
  for (int off = 1; off < 256; off <<= 1) {
    int x = sh[t];
    int y = (t >= off) ? sh[t - off] : 0;
    __syncthreads();
    sh[t] = x + y;
    __syncthreads();
  }
  int run = bsum_ex[b] + ((t == 0) ? 0 : sh[t - 1]);
  #pragma unroll
  for (int i = 0; i < 4; ++i) {
    if (base + i < n) {
      offsets[base + i] = run;
      int pb = run;
      #pragma unroll
      for (int q = 0; q < 8; ++q) {
        cnt8[q * n + base + i] = pb;  // partition base (in-place)
        pb += cq[i][q];
      }
      for (int j = run + c[i]; j < run + v[i]; ++j) csr[j] = (u32)n;  // sentinel pads
      run += v[i];
    }
  }
  if (b == 0 && t == 0) dinv[n] = 0.f;  // sentinel: contribution = 0
}

// ---------------- fused layer-1 GEMM (blocks [0,mmb)) + scatter (rest) ----------------
__global__ __launch_bounds__(256, 4) void k_mm1_scatter(
    const int* __restrict__ ids, const float* __restrict__ emb,
    const float* __restrict__ W1, u8* __restrict__ out, int n, int mmb,
    const int* __restrict__ src, const int* __restrict__ dst,
    const int* __restrict__ rank, const int* __restrict__ pbase,
    u32* __restrict__ csr, int e_count) {
  if ((int)blockIdx.x >= mmb) {
    int eb = blockIdx.x - mmb;
    int e = eb * 256 + threadIdx.x;
    if (e < e_count) {
      int p = eb & 7;  // matches k_count_rank's blockIdx&7
      int d = dst[e];
      int pos = pbase[p * n + d] + rank[e];
      __builtin_nontemporal_store((u32)src[e], &csr[pos]);
    }
    return;
  }

  const int lane = threadIdx.x & 63;
  const int w = threadIdx.x >> 6;
  const int r = blockIdx.x * 256 + w * 64 + lane;
  const int rid = ids[(r < n) ? r : (n - 1)];
  const float4* __restrict__ xrow = reinterpret_cast<const float4*>(emb + (size_t)rid * 128);

  float acc[64];
  #pragma unroll
  for (int j = 0; j < 64; ++j) acc[j] = 0.f;

  #pragma unroll 1
  for (int s = 0; s < 4; ++s) {
    float4 xb[8];
    #pragma unroll
    for (int i = 0; i < 8; ++i) xb[i] = xrow[s * 8 + i];
    const float* __restrict__ wbase = W1 + (size_t)(s * 32) * 64;
    #pragma unroll
    for (int i = 0; i < 8; ++i) {
      const float* __restrict__ w0 = wbase + (i * 4) * 64;
      #pragma unroll
      for (int j = 0; j < 64; ++j) {
        acc[j] = fmaf(xb[i].x, w0[j], acc[j]);
        acc[j] = fmaf(xb[i].y, w0[64 + j], acc[j]);
        acc[j] = fmaf(xb[i].z, w0[128 + j], acc[j]);
        acc[j] = fmaf(xb[i].w, w0[192 + j], acc[j]);
      }
    }
  }

  if (r < n) {
    u8* op = out + (size_t)r * 64;
    #pragma unroll
    for (int q = 0; q < 4; ++q) {
      uint4 pk;
      pk.x = fp8e4(acc[q * 16 + 0] * FSCALE, acc[q * 16 + 1] * FSCALE,
                   acc[q * 16 + 2] * FSCALE, acc[q * 16 + 3] * FSCALE);
      pk.y = fp8e4(acc[q * 16 + 4] * FSCALE, acc[q * 16 + 5] * FSCALE,
                   acc[q * 16 + 6] * FSCALE, acc[q * 16 + 7] * FSCALE);
      pk.z = fp8e4(acc[q * 16 + 8] * FSCALE, acc[q * 16 + 9] * FSCALE,
                   acc[q * 16 + 10] * FSCALE, acc[q * 16 + 11] * FSCALE);
      pk.w = fp8e4(acc[q * 16 + 12] * FSCALE, acc[q * 16 + 13] * FSCALE,
                   acc[q * 16 + 14] * FSCALE, acc[q * 16 + 15] * FSCALE);
      *reinterpret_cast<uint4*>(op + q * 16) = pk;
    }
  }
}

// ---------------- fused aggregation + next-layer GEMM ----------------
// csr = u32 src; features fp8 scaled by S; dinv scaled by 1/sqrt(S) -> every
// 2-dinv product cancels S exactly. Per 8-batch (one node): 8 byte-gathers ->
// tmp = sum fp8d(x)*dinv[src] -> acc_node = fma(tmp, dinv[node], acc_node).

template <bool FINAL>
__global__ __launch_bounds__(256) void k_agg(const u8* __restrict__ xw, const u32* __restrict__ csr,
                                             const int* __restrict__ offs, const float* __restrict__ dinv,
                                             const float* __restrict__ bias, const float* __restrict__ Wn,
                                             u8* __restrict__ out, int n) {
  const int lane = threadIdx.x & 63;
  const int w = threadIdx.x >> 6;
  const float bl = bias[lane];
  const int ngroups = (n + 3) >> 2;
  const int nwaves = gridDim.x * 4;

  for (int grp = blockIdx.x * 4 + w; grp < ngroups; grp += nwaves) {
    const int v0 = grp * 4;
    const int c1 = (v0 + 1 < n) ? v0 + 1 : n;
    const int c2 = (v0 + 2 < n) ? v0 + 2 : n;
    const int c3 = (v0 + 3 < n) ? v0 + 3 : n;
    const int b0 = offs[v0], b1 = offs[c1], b2 = offs[c2], b3 = offs[c3];
    const int b4 = offs[(v0 + 4 < n) ? v0 + 4 : n];

    const float d0 = dinv[v0];
    const float d1 = dinv[(c1 < n) ? c1 : v0];
    const float d2 = dinv[(c2 < n) ? c2 : v0];
    const float d3 = dinv[(c3 < n) ? c3 : v0];
    float acc0 = fmaf(fp8d(xw[(size_t)v0 * 64 + lane]) * d0, d0, bl);
    float acc1 = (c1 < n) ? fmaf(fp8d(xw[(size_t)c1 * 64 + lane]) * d1, d1, bl) : 0.f;
    float acc2 = (c2 < n) ? fmaf(fp8d(xw[(size_t)c2 * 64 + lane]) * d2, d2, bl) : 0.f;
    float acc3 = (c3 < n) ? fmaf(fp8d(xw[(size_t)c3 * 64 + lane]) * d3, d3, bl) : 0.f;

    int e = b0;
    while (e < b4) {
      int cc = b4 - e;
      cc = (cc < 64) ? cc : 64;
      u32 ce = (u32)n;
      if (lane < cc) ce = csr[e + lane];
      // uniform 8-edge batches; each batch maps to exactly one node
      for (int bs = 0; bs < cc; bs += 8) {
        float xv[8], dv[8];
        #pragma unroll
        for (int t = 0; t < 8; ++t) {
          int sb = __builtin_amdgcn_readlane((int)ce, bs + t);
          xv[t] = fp8d(xw[(size_t)sb * 64 + lane]);
          dv[t] = dinv[sb];
        }
        float tmp = 0.f;
        #pragma unroll
        for (int t = 0; t < 8; ++t) tmp = fmaf(xv[t], dv[t], tmp);
        const int ep = e + bs;  // wave-uniform
        if (ep < b1) acc0 = fmaf(tmp, d0, acc0);
        else if (ep < b2) acc1 = fmaf(tmp, d1, acc1);
        else if (ep < b3) acc2 = fmaf(tmp, d2, acc2);
        else acc3 = fmaf(tmp, d3, acc3);
      }
      e += cc;
    }

    float h0 = fmaxf(acc0, 0.f), h1 = fmaxf(acc1, 0.f);
    float h2 = fmaxf(acc2, 0.f), h3 = fmaxf(acc3, 0.f);
    if constexpr (FINAL) {
      out[(size_t)v0 * 64 + lane] = (u8)fp8e1(h0 * FSCALE);
      if (c1 < n) out[(size_t)c1 * 64 + lane] = (u8)fp8e1(h1 * FSCALE);
      if (c2 < n) out[(size_t)c2 * 64 + lane] = (u8)fp8e1(h2 * FSCALE);
      if (c3 < n) out[(size_t)c3 * 64 + lane] = (u8)fp8e1(h3 * FSCALE);
    } else {
      const int hb0 = __float_as_int(h0), hb1 = __float_as_int(h1);
      const int hb2 = __float_as_int(h2), hb3 = __float_as_int(h3);
      float o0 = 0.f, o1 = 0.f, o2 = 0.f, o3 = 0.f;
      #pragma unroll
      for (int k = 0; k < 64; ++k) {
        float wk = Wn[k * 64 + lane];
        o0 = fmaf(__int_as_float(__builtin_amdgcn_readlane(hb0, k)), wk, o0);
        o1 = fmaf(__int_as_float(__builtin_amdgcn_readlane(hb1, k)), wk, o1);
        o2 = fmaf(__int_as_float(__builtin_amdgcn_readlane(hb2, k)), wk, o2);
        o3 = fmaf(__int_as_float(__builtin_amdgcn_readlane(hb3, k)), wk, o3);
      }
      out[(size_t)v0 * 64 + lane] = (u8)fp8e1(o0 * FSCALE);
      if (c1 < n) out[(size_t)c1 * 64 + lane] = (u8)fp8e1(o1 * FSCALE);
      if (c2 < n) out[(size_t)c2 * 64 + lane] = (u8)fp8e1(o2 * FSCALE);
      if (c3 < n) out[(size_t)c3 * 64 + lane] = (u8)fp8e1(o3 * FSCALE);
    }
  }
}

// ---------------- pooling + MLP head + sigmoid ----------------
__global__ __launch_bounds__(256) void k_pool(const u8* __restrict__ x, const int* __restrict__ batch, int n,
                                              const float* __restrict__ Wf1, const float* __restrict__ bf1,
                                              const float* __restrict__ Wf2, const float* __restrict__ bf2,
                                              float* __restrict__ out) {
  int g = blockIdx.x;
  int tid = threadIdx.x, lane = tid & 63, w = tid >> 6;
  int a = 0, b = n;
  while (a < b) { int m = (a + b) >> 1; if (batch[m] < g) a = m + 1; else b = m; }
  int lo = a;
  b = n;
  while (a < b) { int m = (a + b) >> 1; if (batch[m] < g + 1) a = m + 1; else b = m; }
  int hi = a;

  float acc = 0.f;
  for (int r = lo + w; r < hi; r += 4) acc += fp8d(x[(size_t)r * 64 + lane]);
  __shared__ float red[4][64];
  __shared__ float mean[64];
  red[w][lane] = acc;
  __syncthreads();
  if (w == 0) {
    float s = red[0][lane] + red[1][lane] + red[2][lane] + red[3][lane];
    mean[lane] = s / (fmaxf((float)(hi - lo), 1.0f) * FSCALE);
  }
  __syncthreads();
  if (w == 0) {
    float h = bf1[lane];
    #pragma unroll
    for (int k = 0; k < 64; ++k) h = fmaf(mean[k], Wf1[k * 64 + lane], h);
    h = fmaxf(h, 0.f);
    float vv = h * Wf2[lane];
    for (int off = 32; off > 0; off >>= 1) vv += __shfl_down(vv, off, 64);
    if (lane == 0) out[g] = 1.0f / (1.0f + expf(-(vv + bf2[0])));
  }
}

static inline char* align256(char* p) {
  return (char*)(((uintptr_t)p + 255) & ~(uintptr_t)255);
}

extern "C" void kernel_launch(void* const* d_in, const int* in_sizes, int n_in,
                              void* d_out, int out_size, void* d_ws, size_t ws_size,
                              hipStream_t stream) {
  const int*   x_ids = (const int*)d_in[0];
  const int*   edge  = (const int*)d_in[1];
  const int*   batch = (const int*)d_in[2];
  const float* emb   = (const float*)d_in[3];
  const float* W1    = (const float*)d_in[4];
  const float* b1    = (const float*)d_in[5];
  const float* W2    = (const float*)d_in[6];
  const float* b2    = (const float*)d_in[7];
  const float* W3    = (const float*)d_in[8];
  const float* b3    = (const float*)d_in[9];
  const float* Wf1   = (const float*)d_in[10];
  const float* bf1   = (const float*)d_in[11];
  const float* Wf2   = (const float*)d_in[12];
  const float* bf2   = (const float*)d_in[13];
  float* out = (float*)d_out;

  const int N = in_sizes[0];
  const int E = in_sizes[1] / 2;
  const int G = out_size;
  const int* e_src = edge;
  const int* e_dst = edge + E;

  const size_t EPAD = (size_t)E + 8 * (size_t)(N + 1) + 64;  // padded csr capacity

  // workspace layout (fp8 feature buffers, N+1 rows for sentinel)
  char* p = (char*)d_ws;
  u8*    bufA = (u8*)p;               p = align256(p + (size_t)(N + 1) * 64);
  u8*    bufB = (u8*)p;               p = align256(p + (size_t)(N + 1) * 64);
  u32*   csr  = (u32*)p;              p = align256(p + EPAD * 4);
  int*   rank = (int*)p;              p = align256(p + (size_t)E * 4);
  float* dinv = (float*)p;            p = align256(p + (size_t)(N + 1) * 4);
  int*   cnt8 = (int*)p;              p = align256(p + (size_t)8 * N * 4);
  int*   offs = (int*)p;              p = align256(p + (size_t)(N + 1) * 4);
  int*   bsum = (int*)p;              p = align256(p + (size_t)1024 * 4);
  (void)ws_size; (void)n_in;

  const int nb_scan = (N + 1023) / 1024;  // 98 for N=100000 (<=128)
  dim3 blk(256);

  // CSR build
  k_init<<<dim3(512), blk, 0, stream>>>(cnt8, 8 * N, bufA + (size_t)N * 64, bufB + (size_t)N * 64);
  k_count_rank<<<dim3((E + 255) / 256), blk, 0, stream>>>(e_dst, cnt8, rank, E, N);
  k_scan1<<<dim3(nb_scan), blk, 0, stream>>>(cnt8, N, bsum);
  k_scan2<<<dim3(1), dim3(128), 0, stream>>>(bsum, nb_scan, offs + N);
  k_scan3<<<dim3(nb_scan), blk, 0, stream>>>(cnt8, N, bsum, offs, dinv, csr);

  // fused: layer-1 GEMM (blocks [0,mmb)) overlapped with CSR scatter (rest)
  const int mmb = (N + 255) / 256;
  const int scb = (E + 255) / 256;
  k_mm1_scatter<<<dim3(mmb + scb), blk, 0, stream>>>(
      x_ids, emb, W1, bufA, N, mmb,
      e_src, e_dst, rank, cnt8, csr, E);

  // fused conv+next-GEMM chain (4 nodes/wave, grid-stride)
  k_agg<false><<<dim3(2048), blk, 0, stream>>>(bufA, csr, offs, dinv, b1, W2, bufB, N);
  k_agg<false><<<dim3(2048), blk, 0, stream>>>(bufB, csr, offs, dinv, b2, W3, bufA, N);
  k_agg<true><<<dim3(2048), blk, 0, stream>>>(bufA, csr, offs, dinv, b3, nullptr, bufB, N);

  // pool + MLP head
  k_pool<<<dim3(G), blk, 0, stream>>>(bufB, batch, N, Wf1, bf1, Wf2, bf2, out);
}

// Round 15
// 386.028 us; speedup vs baseline: 1.0358x; 1.0309x over previous
//
#include <hip/hip_runtime.h>
#include <hip/hip_bf16.h>
#include <hip/hip_fp8.h>

// GCN, fp8(e4m3) PRE-MULTIPLIED node features z[v] = h[v]*dinv[v]*S, fp32 accum.
//  Per-edge work: 1 readlane + 1 byte-gather + cvt-add (no dinv lookup).
//  Agg inner loop: masked 64-edge chunks, always 8 batches, static 2-deep
//  ping-pong pipeline (16 gathers in flight). dsc[v] = dinv[v]/S.
//  CSR build: 8 XCD-pinned counters, rank capture, atomic-free scatter fused
//  with layer-1 GEMM. 3x k_agg (fused next-W GEMM); k_pool.

typedef unsigned char u8;
typedef unsigned short u16;
typedef unsigned int u32;

#define FSCALE 256.0f
#define SINV (1.0f / 256.0f)
#define S2 65536.0f

__device__ __forceinline__ float fp8d(u32 b) {
#if __has_builtin(__builtin_amdgcn_cvt_f32_fp8)
  return __builtin_amdgcn_cvt_f32_fp8((int)b, 0);
#else
  __hip_fp8_e4m3 t; t.__x = (__hip_fp8_storage_t)b; return (float)t;
#endif
}
__device__ __forceinline__ u32 fp8e1(float f) {
#if __has_builtin(__builtin_amdgcn_cvt_pk_fp8_f32)
  return (u32)__builtin_amdgcn_cvt_pk_fp8_f32(f, 0.f, 0, false) & 0xffu;
#else
  __hip_fp8_e4m3 t(f); return (u32)t.__x;
#endif
}
__device__ __forceinline__ u32 fp8e4(float f0, float f1, float f2, float f3) {
#if __has_builtin(__builtin_amdgcn_cvt_pk_fp8_f32)
  int r = 0;
  r = __builtin_amdgcn_cvt_pk_fp8_f32(f0, f1, r, false);
  r = __builtin_amdgcn_cvt_pk_fp8_f32(f2, f3, r, true);
  return (u32)r;
#else
  __hip_fp8_e4m3 a(f0), b(f1), c(f2), d(f3);
  return (u32)a.__x | ((u32)b.__x << 8) | ((u32)c.__x << 16) | ((u32)d.__x << 24);
#endif
}

// ---------------- init: zero partition counters + sentinel feature rows ----------------
__global__ __launch_bounds__(256) void k_init(int* __restrict__ cnt8, int n8,
                                              u8* __restrict__ rowA, u8* __restrict__ rowB) {
  int i = blockIdx.x * blockDim.x + threadIdx.x;
  int stride = gridDim.x * blockDim.x;
  for (; i < n8; i += stride) cnt8[i] = 0;
  if (blockIdx.x == 0 && threadIdx.x < 64) {
    rowA[threadIdx.x] = 0;
    rowB[threadIdx.x] = 0;
  }
}

// count in-degree into partition (blockIdx&7) counter; rank = atomic return.
__global__ __launch_bounds__(256) void k_count_rank(const int* __restrict__ dst, int* __restrict__ cnt8,
                                                    int* __restrict__ rank, int e_count, int n) {
  int e = blockIdx.x * blockDim.x + threadIdx.x;
  if (e < e_count) {
    int p = blockIdx.x & 7;
    rank[e] = atomicAdd(&cnt8[p * n + dst[e]], 1);
  }
}

// scan over PADDED totals ((sum8+7)&~7)
__global__ __launch_bounds__(256) void k_scan1(const int* __restrict__ cnt8, int n, int* __restrict__ bsum) {
  __shared__ int s[256];
  int b = blockIdx.x, t = threadIdx.x;
  int base = b * 1024;
  int sum = 0;
  #pragma unroll
  for (int i = 0; i < 4; ++i) {
    int idx = base + t + i * 256;
    if (idx < n) {
      int c = 0;
      #pragma unroll
      for (int q = 0; q < 8; ++q) c += cnt8[q * n + idx];
      sum += (c + 7) & ~7;
    }
  }
  s[t] = sum; __syncthreads();
  for (int off = 128; off > 0; off >>= 1) {
    if (t < off) s[t] += s[t + off];
    __syncthreads();
  }
  if (t == 0) bsum[b] = s[0];
}

__global__ __launch_bounds__(128) void k_scan2(int* __restrict__ bsum, int nb, int* __restrict__ total_out) {
  __shared__ int sh[128];
  int t = threadIdx.x;
  sh[t] = (t < nb) ? bsum[t] : 0;
  __syncthreads();
  for (int off = 1; off < 128; off <<= 1) {
    int x = sh[t];
    int y = (t >= off) ? sh[t - off] : 0;
    __syncthreads();
    sh[t] = x + y;
    __syncthreads();
  }
  if (t < nb) bsum[t] = (t == 0) ? 0 : sh[t - 1];
  if (t == 0) *total_out = sh[127];
}

// scan3: padded offsets, dsc = dinv/S, per-partition bases (in-place), pads.
__global__ __launch_bounds__(256) void k_scan3(int* __restrict__ cnt8, int n,
                                               const int* __restrict__ bsum_ex, int* __restrict__ offsets,
                                               float* __restrict__ dsc, u32* __restrict__ csr) {
  __shared__ int sh[256];
  int b = blockIdx.x, t = threadIdx.x;
  int base = b * 1024 + t * 4;
  int cq[4][8];
  int c[4], v[4];
  #pragma unroll
  for (int i = 0; i < 4; ++i) {
    c[i] = 0;
    #pragma unroll
    for (int q = 0; q < 8; ++q) {
      int x = (base + i < n) ? cnt8[q * n + base + i] : 0;
      cq[i][q] = x;
      c[i] += x;
    }
    v[i] = (c[i] + 7) & ~7;
    if (base + i < n) dsc[base + i] = rsqrtf((float)c[i] + 1.0f) * SINV;
  }
  sh[t] = v[0] + v[1] + v[2] + v[3];
  __syncthreads();
  for (int off = 1; off < 256; off <<= 1) {
    int x = sh[t];
    int y = (t >= off) ? sh[t - off] : 0;
    __syncthreads();
    sh[t] = x + y;
    __syncthreads();
  }
  int run = bsum_ex[b] + ((t == 0) ? 0 : sh[t - 1]);
  #pragma unroll
  for (int i = 0; i < 4; ++i) {
    if (base + i < n) {
      offsets[base + i] = run;
      int pb = run;
      #pragma unroll
      for (int q = 0; q < 8; ++q) {
        cnt8[q * n + base + i] = pb;  // partition base (in-place)
        pb += cq[i][q];
      }
      for (int j = run + c[i]; j < run + v[i]; ++j) csr[j] = (u32)n;  // sentinel pads
      run += v[i];
    }
  }
  if (b == 0 && t == 0) dsc[n] = 0.f;
}

// ---------------- fused layer-1 GEMM (blocks [0,mmb)) + scatter (rest) ----------------
// mm1 stores z1 = (emb@W1) * dinv[r] * S  (= acc * dsc[r] * S^2).
__global__ __launch_bounds__(256, 4) void k_mm1_scatter(
    const int* __restrict__ ids, const float* __restrict__ emb,
    const float* __restrict__ W1, u8* __restrict__ out, int n, int mmb,
    const int* __restrict__ src, const int* __restrict__ dst,
    const int* __restrict__ rank, const int* __restrict__ pbase,
    const float* __restrict__ dsc, u32* __restrict__ csr, int e_count) {
  if ((int)blockIdx.x >= mmb) {
    int eb = blockIdx.x - mmb;
    int e = eb * 256 + threadIdx.x;
    if (e < e_count) {
      int p = eb & 7;  // matches k_count_rank's blockIdx&7
      int d = dst[e];
      int pos = pbase[p * n + d] + rank[e];
      __builtin_nontemporal_store((u32)src[e], &csr[pos]);
    }
    return;
  }

  const int lane = threadIdx.x & 63;
  const int w = threadIdx.x >> 6;
  const int r = blockIdx.x * 256 + w * 64 + lane;
  const int rc = (r < n) ? r : (n - 1);
  const int rid = ids[rc];
  const float zs = dsc[rc] * S2;  // dinv[r] * S
  const float4* __restrict__ xrow = reinterpret_cast<const float4*>(emb + (size_t)rid * 128);

  float acc[64];
  #pragma unroll
  for (int j = 0; j < 64; ++j) acc[j] = 0.f;

  #pragma unroll 1
  for (int s = 0; s < 4; ++s) {
    float4 xb[8];
    #pragma unroll
    for (int i = 0; i < 8; ++i) xb[i] = xrow[s * 8 + i];
    const float* __restrict__ wbase = W1 + (size_t)(s * 32) * 64;
    #pragma unroll
    for (int i = 0; i < 8; ++i) {
      const float* __restrict__ w0 = wbase + (i * 4) * 64;
      #pragma unroll
      for (int j = 0; j < 64; ++j) {
        acc[j] = fmaf(xb[i].x, w0[j], acc[j]);
        acc[j] = fmaf(xb[i].y, w0[64 + j], acc[j]);
        acc[j] = fmaf(xb[i].z, w0[128 + j], acc[j]);
        acc[j] = fmaf(xb[i].w, w0[192 + j], acc[j]);
      }
    }
  }

  if (r < n) {
    u8* op = out + (size_t)r * 64;
    #pragma unroll
    for (int q = 0; q < 4; ++q) {
      uint4 pk;
      pk.x = fp8e4(acc[q * 16 + 0] * zs, acc[q * 16 + 1] * zs,
                   acc[q * 16 + 2] * zs, acc[q * 16 + 3] * zs);
      pk.y = fp8e4(acc[q * 16 + 4] * zs, acc[q * 16 + 5] * zs,
                   acc[q * 16 + 6] * zs, acc[q * 16 + 7] * zs);
      pk.z = fp8e4(acc[q * 16 + 8] * zs, acc[q * 16 + 9] * zs,
                   acc[q * 16 + 10] * zs, acc[q * 16 + 11] * zs);
      pk.w = fp8e4(acc[q * 16 + 12] * zs, acc[q * 16 + 13] * zs,
                   acc[q * 16 + 14] * zs, acc[q * 16 + 15] * zs);
      *reinterpret_cast<uint4*>(op + q * 16) = pk;
    }
  }
}

// ---------------- fused aggregation + next-layer GEMM ----------------
// z = h*dinv*S (fp8). tmp = sum fp8d(z[src]); acc += tmp * dsc[dst].
// Self: acc = fma(fp8d(z[v]), dsc[v], bias). Chunks always run 8 batches
// (masked ce -> sentinel n, z-row n = 0): static 2-deep ping-pong pipeline.

#define G8(dstreg, OFF)                                                      \
  _Pragma("unroll")                                                          \
  for (int t_ = 0; t_ < 8; ++t_) {                                           \
    int sb_ = __builtin_amdgcn_readlane((int)ce, (OFF) + t_);                \
    dstreg[t_] = (u32)z[(size_t)sb_ * 64 + lane];                            \
  }

#define C8(srcreg, OFF)                                                      \
  {                                                                          \
    float tmp_ = 0.f;                                                        \
    _Pragma("unroll")                                                        \
    for (int t_ = 0; t_ < 8; ++t_) tmp_ += fp8d(srcreg[t_]);                 \
    const int ep_ = e + (OFF);                                               \
    if (ep_ < b1) acc0 = fmaf(tmp_, d0, acc0);                               \
    else if (ep_ < b2) acc1 = fmaf(tmp_, d1, acc1);                          \
    else if (ep_ < b3) acc2 = fmaf(tmp_, d2, acc2);                          \
    else acc3 = fmaf(tmp_, d3, acc3);                                        \
  }

template <bool FINAL>
__global__ __launch_bounds__(256) void k_agg(const u8* __restrict__ z, const u32* __restrict__ csr,
                                             const int* __restrict__ offs, const float* __restrict__ dsc,
                                             const float* __restrict__ bias, const float* __restrict__ Wn,
                                             u8* __restrict__ out, int n) {
  const int lane = threadIdx.x & 63;
  const int w = threadIdx.x >> 6;
  const float bl = bias[lane];
  const int ngroups = (n + 3) >> 2;
  const int nwaves = gridDim.x * 4;

  for (int grp = blockIdx.x * 4 + w; grp < ngroups; grp += nwaves) {
    const int v0 = grp * 4;
    const int c1 = (v0 + 1 < n) ? v0 + 1 : n;
    const int c2 = (v0 + 2 < n) ? v0 + 2 : n;
    const int c3 = (v0 + 3 < n) ? v0 + 3 : n;
    const int b0 = offs[v0], b1 = offs[c1], b2 = offs[c2], b3 = offs[c3];
    const int b4 = offs[(v0 + 4 < n) ? v0 + 4 : n];

    const float d0 = dsc[v0];
    const float d1 = dsc[(c1 < n) ? c1 : v0];
    const float d2 = dsc[(c2 < n) ? c2 : v0];
    const float d3 = dsc[(c3 < n) ? c3 : v0];
    float acc0 = fmaf(fp8d(z[(size_t)v0 * 64 + lane]), d0, bl);
    float acc1 = (c1 < n) ? fmaf(fp8d(z[(size_t)c1 * 64 + lane]), d1, bl) : 0.f;
    float acc2 = (c2 < n) ? fmaf(fp8d(z[(size_t)c2 * 64 + lane]), d2, bl) : 0.f;
    float acc3 = (c3 < n) ? fmaf(fp8d(z[(size_t)c3 * 64 + lane]), d3, bl) : 0.f;

    int e = b0;
    while (e < b4) {
      u32 ce = (u32)n;
      if (lane < b4 - e) ce = csr[e + lane];
      u32 gA[8], gB[8];
      G8(gA, 0)
      G8(gB, 8)
      C8(gA, 0)
      G8(gA, 16)
      C8(gB, 8)
      G8(gB, 24)
      C8(gA, 16)
      G8(gA, 32)
      C8(gB, 24)
      G8(gB, 40)
      C8(gA, 32)
      G8(gA, 48)
      C8(gB, 40)
      G8(gB, 56)
      C8(gA, 48)
      C8(gB, 56)
      e += 64;
    }

    float h0 = fmaxf(acc0, 0.f), h1 = fmaxf(acc1, 0.f);
    float h2 = fmaxf(acc2, 0.f), h3 = fmaxf(acc3, 0.f);
    if constexpr (FINAL) {
      out[(size_t)v0 * 64 + lane] = (u8)fp8e1(h0 * FSCALE);
      if (c1 < n) out[(size_t)c1 * 64 + lane] = (u8)fp8e1(h1 * FSCALE);
      if (c2 < n) out[(size_t)c2 * 64 + lane] = (u8)fp8e1(h2 * FSCALE);
      if (c3 < n) out[(size_t)c3 * 64 + lane] = (u8)fp8e1(h3 * FSCALE);
    } else {
      const int hb0 = __float_as_int(h0), hb1 = __float_as_int(h1);
      const int hb2 = __float_as_int(h2), hb3 = __float_as_int(h3);
      float o0 = 0.f, o1 = 0.f, o2 = 0.f, o3 = 0.f;
      #pragma unroll
      for (int k = 0; k < 64; ++k) {
        float wk = Wn[k * 64 + lane];
        o0 = fmaf(__int_as_float(__builtin_amdgcn_readlane(hb0, k)), wk, o0);
        o1 = fmaf(__int_as_float(__builtin_amdgcn_readlane(hb1, k)), wk, o1);
        o2 = fmaf(__int_as_float(__builtin_amdgcn_readlane(hb2, k)), wk, o2);
        o3 = fmaf(__int_as_float(__builtin_amdgcn_readlane(hb3, k)), wk, o3);
      }
      // store z' = o * dinv * S = o * dsc * S^2
      out[(size_t)v0 * 64 + lane] = (u8)fp8e1(o0 * d0 * S2);
      if (c1 < n) out[(size_t)c1 * 64 + lane] = (u8)fp8e1(o1 * d1 * S2);
      if (c2 < n) out[(size_t)c2 * 64 + lane] = (u8)fp8e1(o2 * d2 * S2);
      if (c3 < n) out[(size_t)c3 * 64 + lane] = (u8)fp8e1(o3 * d3 * S2);
    }
  }
}

// ---------------- pooling + MLP head + sigmoid ----------------
__global__ __launch_bounds__(256) void k_pool(const u8* __restrict__ x, const int* __restrict__ batch, int n,
                                              const float* __restrict__ Wf1, const float* __restrict__ bf1,
                                              const float* __restrict__ Wf2, const float* __restrict__ bf2,
                                              float* __restrict__ out) {
  int g = blockIdx.x;
  int tid = threadIdx.x, lane = tid & 63, w = tid >> 6;
  int a = 0, b = n;
  while (a < b) { int m = (a + b) >> 1; if (batch[m] < g) a = m + 1; else b = m; }
  int lo = a;
  b = n;
  while (a < b) { int m = (a + b) >> 1; if (batch[m] < g + 1) a = m + 1; else b = m; }
  int hi = a;

  float acc = 0.f;
  for (int r = lo + w; r < hi; r += 4) acc += fp8d(x[(size_t)r * 64 + lane]);
  __shared__ float red[4][64];
  __shared__ float mean[64];
  red[w][lane] = acc;
  __syncthreads();
  if (w == 0) {
    float s = red[0][lane] + red[1][lane] + red[2][lane] + red[3][lane];
    mean[lane] = s / (fmaxf((float)(hi - lo), 1.0f) * FSCALE);
  }
  __syncthreads();
  if (w == 0) {
    float h = bf1[lane];
    #pragma unroll
    for (int k = 0; k < 64; ++k) h = fmaf(mean[k], Wf1[k * 64 + lane], h);
    h = fmaxf(h, 0.f);
    float vv = h * Wf2[lane];
    for (int off = 32; off > 0; off >>= 1) vv += __shfl_down(vv, off, 64);
    if (lane == 0) out[g] = 1.0f / (1.0f + expf(-(vv + bf2[0])));
  }
}

static inline char* align256(char* p) {
  return (char*)(((uintptr_t)p + 255) & ~(uintptr_t)255);
}

extern "C" void kernel_launch(void* const* d_in, const int* in_sizes, int n_in,
                              void* d_out, int out_size, void* d_ws, size_t ws_size,
                              hipStream_t stream) {
  const int*   x_ids = (const int*)d_in[0];
  const int*   edge  = (const int*)d_in[1];
  const int*   batch = (const int*)d_in[2];
  const float* emb   = (const float*)d_in[3];
  const float* W1    = (const float*)d_in[4];
  const float* b1    = (const float*)d_in[5];
  const float* W2    = (const float*)d_in[6];
  const float* b2    = (const float*)d_in[7];
  const float* W3    = (const float*)d_in[8];
  const float* b3    = (const float*)d_in[9];
  const float* Wf1   = (const float*)d_in[10];
  const float* bf1   = (const float*)d_in[11];
  const float* Wf2   = (const float*)d_in[12];
  const float* bf2   = (const float*)d_in[13];
  float* out = (float*)d_out;

  const int N = in_sizes[0];
  const int E = in_sizes[1] / 2;
  const int G = out_size;
  const int* e_src = edge;
  const int* e_dst = edge + E;

  const size_t EPAD = (size_t)E + 8 * (size_t)(N + 1) + 128;  // padded csr capacity (+chunk slack)

  // workspace layout (fp8 feature buffers, N+1 rows for sentinel)
  char* p = (char*)d_ws;
  u8*    bufA = (u8*)p;               p = align256(p + (size_t)(N + 1) * 64);
  u8*    bufB = (u8*)p;               p = align256(p + (size_t)(N + 1) * 64);
  u32*   csr  = (u32*)p;              p = align256(p + EPAD * 4);
  int*   rank = (int*)p;              p = align256(p + (size_t)E * 4);
  float* dsc  = (float*)p;            p = align256(p + (size_t)(N + 1) * 4);
  int*   cnt8 = (int*)p;              p = align256(p + (size_t)8 * N * 4);
  int*   offs = (int*)p;              p = align256(p + (size_t)(N + 1) * 4);
  int*   bsum = (int*)p;              p = align256(p + (size_t)1024 * 4);
  (void)ws_size; (void)n_in;

  const int nb_scan = (N + 1023) / 1024;  // 98 for N=100000 (<=128)
  dim3 blk(256);

  // CSR build
  k_init<<<dim3(512), blk, 0, stream>>>(cnt8, 8 * N, bufA + (size_t)N * 64, bufB + (size_t)N * 64);
  k_count_rank<<<dim3((E + 255) / 256), blk, 0, stream>>>(e_dst, cnt8, rank, E, N);
  k_scan1<<<dim3(nb_scan), blk, 0, stream>>>(cnt8, N, bsum);
  k_scan2<<<dim3(1), dim3(128), 0, stream>>>(bsum, nb_scan, offs + N);
  k_scan3<<<dim3(nb_scan), blk, 0, stream>>>(cnt8, N, bsum, offs, dsc, csr);

  // fused: layer-1 GEMM (blocks [0,mmb)) overlapped with CSR scatter (rest)
  const int mmb = (N + 255) / 256;
  const int scb = (E + 255) / 256;
  k_mm1_scatter<<<dim3(mmb + scb), blk, 0, stream>>>(
      x_ids, emb, W1, bufA, N, mmb,
      e_src, e_dst, rank, cnt8, dsc, csr, E);

  // fused conv+next-GEMM chain (4 nodes/wave, grid-stride)
  k_agg<false><<<dim3(2048), blk, 0, stream>>>(bufA, csr, offs, dsc, b1, W2, bufB, N);
  k_agg<false><<<dim3(2048), blk, 0, stream>>>(bufB, csr, offs, dsc, b2, W3, bufA, N);
  k_agg<true><<<dim3(2048), blk, 0, stream>>>(bufA, csr, offs, dsc, b3, nullptr, bufB, N);

  // pool + MLP head
  k_pool<<<dim3(G), blk, 0, stream>>>(bufB, batch, N, Wf1, bf1, Wf2, bf2, out);
}

// Round 16
// 356.860 us; speedup vs baseline: 1.1205x; 1.0817x over previous
//
#include <hip/hip_runtime.h>
#include <hip/hip_bf16.h>
#include <hip/hip_fp8.h>

// GCN, fp8(e4m3) PRE-MULTIPLIED node features z[v] = h[v]*dinv[v]*S, fp32 accum.
//  Agg: ONE 4-node group per wave (exact grid, HW dynamic balance), masked
//  64-edge chunks, 4-deep ping-pong pipeline (32 gathers in flight).
//  CSR build: 8 XCD-pinned counters, rank capture, atomic-free scatter fused
//  with layer-1 GEMM. 3x k_agg (fused next-W GEMM); k_pool.

typedef unsigned char u8;
typedef unsigned short u16;
typedef unsigned int u32;

#define FSCALE 256.0f
#define SINV (1.0f / 256.0f)
#define S2 65536.0f

__device__ __forceinline__ float fp8d(u32 b) {
#if __has_builtin(__builtin_amdgcn_cvt_f32_fp8)
  return __builtin_amdgcn_cvt_f32_fp8((int)b, 0);
#else
  __hip_fp8_e4m3 t; t.__x = (__hip_fp8_storage_t)b; return (float)t;
#endif
}
__device__ __forceinline__ u32 fp8e1(float f) {
#if __has_builtin(__builtin_amdgcn_cvt_pk_fp8_f32)
  return (u32)__builtin_amdgcn_cvt_pk_fp8_f32(f, 0.f, 0, false) & 0xffu;
#else
  __hip_fp8_e4m3 t(f); return (u32)t.__x;
#endif
}
__device__ __forceinline__ u32 fp8e4(float f0, float f1, float f2, float f3) {
#if __has_builtin(__builtin_amdgcn_cvt_pk_fp8_f32)
  int r = 0;
  r = __builtin_amdgcn_cvt_pk_fp8_f32(f0, f1, r, false);
  r = __builtin_amdgcn_cvt_pk_fp8_f32(f2, f3, r, true);
  return (u32)r;
#else
  __hip_fp8_e4m3 a(f0), b(f1), c(f2), d(f3);
  return (u32)a.__x | ((u32)b.__x << 8) | ((u32)c.__x << 16) | ((u32)d.__x << 24);
#endif
}

// ---------------- init: zero partition counters + sentinel feature rows ----------------
__global__ __launch_bounds__(256) void k_init(int* __restrict__ cnt8, int n8,
                                              u8* __restrict__ rowA, u8* __restrict__ rowB) {
  int i = blockIdx.x * blockDim.x + threadIdx.x;
  int stride = gridDim.x * blockDim.x;
  for (; i < n8; i += stride) cnt8[i] = 0;
  if (blockIdx.x == 0 && threadIdx.x < 64) {
    rowA[threadIdx.x] = 0;
    rowB[threadIdx.x] = 0;
  }
}

// count in-degree into partition (blockIdx&7) counter; rank = atomic return.
__global__ __launch_bounds__(256) void k_count_rank(const int* __restrict__ dst, int* __restrict__ cnt8,
                                                    int* __restrict__ rank, int e_count, int n) {
  int e = blockIdx.x * blockDim.x + threadIdx.x;
  if (e < e_count) {
    int p = blockIdx.x & 7;
    rank[e] = atomicAdd(&cnt8[p * n + dst[e]], 1);
  }
}

// scan over PADDED totals ((sum8+7)&~7)
__global__ __launch_bounds__(256) void k_scan1(const int* __restrict__ cnt8, int n, int* __restrict__ bsum) {
  __shared__ int s[256];
  int b = blockIdx.x, t = threadIdx.x;
  int base = b * 1024;
  int sum = 0;
  #pragma unroll
  for (int i = 0; i < 4; ++i) {
    int idx = base + t + i * 256;
    if (idx < n) {
      int c = 0;
      #pragma unroll
      for (int q = 0; q < 8; ++q) c += cnt8[q * n + idx];
      sum += (c + 7) & ~7;
    }
  }
  s[t] = sum; __syncthreads();
  for (int off = 128; off > 0; off >>= 1) {
    if (t < off) s[t] += s[t + off];
    __syncthreads();
  }
  if (t == 0) bsum[b] = s[0];
}

__global__ __launch_bounds__(128) void k_scan2(int* __restrict__ bsum, int nb, int* __restrict__ total_out) {
  __shared__ int sh[128];
  int t = threadIdx.x;
  sh[t] = (t < nb) ? bsum[t] : 0;
  __syncthreads();
  for (int off = 1; off < 128; off <<= 1) {
    int x = sh[t];
    int y = (t >= off) ? sh[t - off] : 0;
    __syncthreads();
    sh[t] = x + y;
    __syncthreads();
  }
  if (t < nb) bsum[t] = (t == 0) ? 0 : sh[t - 1];
  if (t == 0) *total_out = sh[127];
}

// scan3: padded offsets, dsc = dinv/S, per-partition bases (in-place), pads.
__global__ __launch_bounds__(256) void k_scan3(int* __restrict__ cnt8, int n,
                                               const int* __restrict__ bsum_ex, int* __restrict__ offsets,
                                               float* __restrict__ dsc, u32* __restrict__ csr) {
  __shared__ int sh[256];
  int b = blockIdx.x, t = threadIdx.x;
  int base = b * 1024 + t * 4;
  int cq[4][8];
  int c[4], v[4];
  #pragma unroll
  for (int i = 0; i < 4; ++i) {
    c[i] = 0;
    #pragma unroll
    for (int q = 0; q < 8; ++q) {
      int x = (base + i < n) ? cnt8[q * n + base + i] : 0;
      cq[i][q] = x;
      c[i] += x;
    }
    v[i] = (c[i] + 7) & ~7;
    if (base + i < n) dsc[base + i] = rsqrtf((float)c[i] + 1.0f) * SINV;
  }
  sh[t] = v[0] + v[1] + v[2] + v[3];
  __syncthreads();
  for (int off = 1; off < 256; off <<= 1) {
    int x = sh[t];
    int y = (t >= off) ? sh[t - off] : 0;
    __syncthreads();
    sh[t] = x + y;
    __syncthreads();
  }
  int run = bsum_ex[b] + ((t == 0) ? 0 : sh[t - 1]);
  #pragma unroll
  for (int i = 0; i < 4; ++i) {
    if (base + i < n) {
      offsets[base + i] = run;
      int pb = run;
      #pragma unroll
      for (int q = 0; q < 8; ++q) {
        cnt8[q * n + base + i] = pb;  // partition base (in-place)
        pb += cq[i][q];
      }
      for (int j = run + c[i]; j < run + v[i]; ++j) csr[j] = (u32)n;  // sentinel pads
      run += v[i];
    }
  }
  if (b == 0 && t == 0) dsc[n] = 0.f;
}

// ---------------- fused layer-1 GEMM (blocks [0,mmb)) + scatter (rest) ----------------
// mm1 stores z1 = (emb@W1) * dinv[r] * S  (= acc * dsc[r] * S^2).
__global__ __launch_bounds__(256, 4) void k_mm1_scatter(
    const int* __restrict__ ids, const float* __restrict__ emb,
    const float* __restrict__ W1, u8* __restrict__ out, int n, int mmb,
    const int* __restrict__ src, const int* __restrict__ dst,
    const int* __restrict__ rank, const int* __restrict__ pbase,
    const float* __restrict__ dsc, u32* __restrict__ csr, int e_count) {
  if ((int)blockIdx.x >= mmb) {
    int eb = blockIdx.x - mmb;
    int e = eb * 256 + threadIdx.x;
    if (e < e_count) {
      int p = eb & 7;  // matches k_count_rank's blockIdx&7
      int d = dst[e];
      int pos = pbase[p * n + d] + rank[e];
      __builtin_nontemporal_store((u32)src[e], &csr[pos]);
    }
    return;
  }

  const int lane = threadIdx.x & 63;
  const int w = threadIdx.x >> 6;
  const int r = blockIdx.x * 256 + w * 64 + lane;
  const int rc = (r < n) ? r : (n - 1);
  const int rid = ids[rc];
  const float zs = dsc[rc] * S2;  // dinv[r] * S
  const float4* __restrict__ xrow = reinterpret_cast<const float4*>(emb + (size_t)rid * 128);

  float acc[64];
  #pragma unroll
  for (int j = 0; j < 64; ++j) acc[j] = 0.f;

  #pragma unroll 1
  for (int s = 0; s < 4; ++s) {
    float4 xb[8];
    #pragma unroll
    for (int i = 0; i < 8; ++i) xb[i] = xrow[s * 8 + i];
    const float* __restrict__ wbase = W1 + (size_t)(s * 32) * 64;
    #pragma unroll
    for (int i = 0; i < 8; ++i) {
      const float* __restrict__ w0 = wbase + (i * 4) * 64;
      #pragma unroll
      for (int j = 0; j < 64; ++j) {
        acc[j] = fmaf(xb[i].x, w0[j], acc[j]);
        acc[j] = fmaf(xb[i].y, w0[64 + j], acc[j]);
        acc[j] = fmaf(xb[i].z, w0[128 + j], acc[j]);
        acc[j] = fmaf(xb[i].w, w0[192 + j], acc[j]);
      }
    }
  }

  if (r < n) {
    u8* op = out + (size_t)r * 64;
    #pragma unroll
    for (int q = 0; q < 4; ++q) {
      uint4 pk;
      pk.x = fp8e4(acc[q * 16 + 0] * zs, acc[q * 16 + 1] * zs,
                   acc[q * 16 + 2] * zs, acc[q * 16 + 3] * zs);
      pk.y = fp8e4(acc[q * 16 + 4] * zs, acc[q * 16 + 5] * zs,
                   acc[q * 16 + 6] * zs, acc[q * 16 + 7] * zs);
      pk.z = fp8e4(acc[q * 16 + 8] * zs, acc[q * 16 + 9] * zs,
                   acc[q * 16 + 10] * zs, acc[q * 16 + 11] * zs);
      pk.w = fp8e4(acc[q * 16 + 12] * zs, acc[q * 16 + 13] * zs,
                   acc[q * 16 + 14] * zs, acc[q * 16 + 15] * zs);
      *reinterpret_cast<uint4*>(op + q * 16) = pk;
    }
  }
}

// ---------------- fused aggregation + next-layer GEMM ----------------
// z = h*dinv*S (fp8). tmp = sum fp8d(z[src]); acc += tmp * dsc[dst].
// ONE 4-node group per wave; chunks always run 8 batches (masked ce ->
// sentinel n, z-row n = 0): static 4-deep ping-pong pipeline (32 in flight).

#define G8(dstreg, OFF)                                                      \
  _Pragma("unroll")                                                          \
  for (int t_ = 0; t_ < 8; ++t_) {                                           \
    int sb_ = __builtin_amdgcn_readlane((int)ce, (OFF) + t_);                \
    dstreg[t_] = (u32)z[(size_t)sb_ * 64 + lane];                            \
  }

#define C8(srcreg, OFF)                                                      \
  {                                                                          \
    float tmp_ = 0.f;                                                        \
    _Pragma("unroll")                                                        \
    for (int t_ = 0; t_ < 8; ++t_) tmp_ += fp8d(srcreg[t_]);                 \
    const int ep_ = e + (OFF);                                               \
    if (ep_ < b1) acc0 = fmaf(tmp_, d0, acc0);                               \
    else if (ep_ < b2) acc1 = fmaf(tmp_, d1, acc1);                          \
    else if (ep_ < b3) acc2 = fmaf(tmp_, d2, acc2);                          \
    else acc3 = fmaf(tmp_, d3, acc3);                                        \
  }

template <bool FINAL>
__global__ __launch_bounds__(256, 4) void k_agg(const u8* __restrict__ z, const u32* __restrict__ csr,
                                                const int* __restrict__ offs, const float* __restrict__ dsc,
                                                const float* __restrict__ bias, const float* __restrict__ Wn,
                                                u8* __restrict__ out, int n) {
  const int lane = threadIdx.x & 63;
  const int w = threadIdx.x >> 6;
  const int ngroups = (n + 3) >> 2;
  const int grp = blockIdx.x * 4 + w;  // exactly one group per wave
  if (grp >= ngroups) return;
  const float bl = bias[lane];

  const int v0 = grp * 4;
  const int c1 = (v0 + 1 < n) ? v0 + 1 : n;
  const int c2 = (v0 + 2 < n) ? v0 + 2 : n;
  const int c3 = (v0 + 3 < n) ? v0 + 3 : n;
  const int b0 = offs[v0], b1 = offs[c1], b2 = offs[c2], b3 = offs[c3];
  const int b4 = offs[(v0 + 4 < n) ? v0 + 4 : n];

  const float d0 = dsc[v0];
  const float d1 = dsc[(c1 < n) ? c1 : v0];
  const float d2 = dsc[(c2 < n) ? c2 : v0];
  const float d3 = dsc[(c3 < n) ? c3 : v0];
  float acc0 = fmaf(fp8d(z[(size_t)v0 * 64 + lane]), d0, bl);
  float acc1 = (c1 < n) ? fmaf(fp8d(z[(size_t)c1 * 64 + lane]), d1, bl) : 0.f;
  float acc2 = (c2 < n) ? fmaf(fp8d(z[(size_t)c2 * 64 + lane]), d2, bl) : 0.f;
  float acc3 = (c3 < n) ? fmaf(fp8d(z[(size_t)c3 * 64 + lane]), d3, bl) : 0.f;

  int e = b0;
  while (e < b4) {
    u32 ce = (u32)n;
    if (lane < b4 - e) ce = csr[e + lane];
    u32 gA[8], gB[8], gC[8], gD[8];
    G8(gA, 0)
    G8(gB, 8)
    G8(gC, 16)
    G8(gD, 24)
    C8(gA, 0)
    G8(gA, 32)
    C8(gB, 8)
    G8(gB, 40)
    C8(gC, 16)
    G8(gC, 48)
    C8(gD, 24)
    G8(gD, 56)
    C8(gA, 32)
    C8(gB, 40)
    C8(gC, 48)
    C8(gD, 56)
    e += 64;
  }

  float h0 = fmaxf(acc0, 0.f), h1 = fmaxf(acc1, 0.f);
  float h2 = fmaxf(acc2, 0.f), h3 = fmaxf(acc3, 0.f);
  if constexpr (FINAL) {
    out[(size_t)v0 * 64 + lane] = (u8)fp8e1(h0 * FSCALE);
    if (c1 < n) out[(size_t)c1 * 64 + lane] = (u8)fp8e1(h1 * FSCALE);
    if (c2 < n) out[(size_t)c2 * 64 + lane] = (u8)fp8e1(h2 * FSCALE);
    if (c3 < n) out[(size_t)c3 * 64 + lane] = (u8)fp8e1(h3 * FSCALE);
  } else {
    const int hb0 = __float_as_int(h0), hb1 = __float_as_int(h1);
    const int hb2 = __float_as_int(h2), hb3 = __float_as_int(h3);
    float o0 = 0.f, o1 = 0.f, o2 = 0.f, o3 = 0.f;
    #pragma unroll
    for (int k = 0; k < 64; ++k) {
      float wk = Wn[k * 64 + lane];
      o0 = fmaf(__int_as_float(__builtin_amdgcn_readlane(hb0, k)), wk, o0);
      o1 = fmaf(__int_as_float(__builtin_amdgcn_readlane(hb1, k)), wk, o1);
      o2 = fmaf(__int_as_float(__builtin_amdgcn_readlane(hb2, k)), wk, o2);
      o3 = fmaf(__int_as_float(__builtin_amdgcn_readlane(hb3, k)), wk, o3);
    }
    // store z' = o * dinv * S = o * dsc * S^2
    out[(size_t)v0 * 64 + lane] = (u8)fp8e1(o0 * d0 * S2);
    if (c1 < n) out[(size_t)c1 * 64 + lane] = (u8)fp8e1(o1 * d1 * S2);
    if (c2 < n) out[(size_t)c2 * 64 + lane] = (u8)fp8e1(o2 * d2 * S2);
    if (c3 < n) out[(size_t)c3 * 64 + lane] = (u8)fp8e1(o3 * d3 * S2);
  }
}

// ---------------- pooling + MLP head + sigmoid ----------------
__global__ __launch_bounds__(256) void k_pool(const u8* __restrict__ x, const int* __restrict__ batch, int n,
                                              const float* __restrict__ Wf1, const float* __restrict__ bf1,
                                              const float* __restrict__ Wf2, const float* __restrict__ bf2,
                                              float* __restrict__ out) {
  int g = blockIdx.x;
  int tid = threadIdx.x, lane = tid & 63, w = tid >> 6;
  int a = 0, b = n;
  while (a < b) { int m = (a + b) >> 1; if (batch[m] < g) a = m + 1; else b = m; }
  int lo = a;
  b = n;
  while (a < b) { int m = (a + b) >> 1; if (batch[m] < g + 1) a = m + 1; else b = m; }
  int hi = a;

  float acc = 0.f;
  for (int r = lo + w; r < hi; r += 4) acc += fp8d(x[(size_t)r * 64 + lane]);
  __shared__ float red[4][64];
  __shared__ float mean[64];
  red[w][lane] = acc;
  __syncthreads();
  if (w == 0) {
    float s = red[0][lane] + red[1][lane] + red[2][lane] + red[3][lane];
    mean[lane] = s / (fmaxf((float)(hi - lo), 1.0f) * FSCALE);
  }
  __syncthreads();
  if (w == 0) {
    float h = bf1[lane];
    #pragma unroll
    for (int k = 0; k < 64; ++k) h = fmaf(mean[k], Wf1[k * 64 + lane], h);
    h = fmaxf(h, 0.f);
    float vv = h * Wf2[lane];
    for (int off = 32; off > 0; off >>= 1) vv += __shfl_down(vv, off, 64);
    if (lane == 0) out[g] = 1.0f / (1.0f + expf(-(vv + bf2[0])));
  }
}

static inline char* align256(char* p) {
  return (char*)(((uintptr_t)p + 255) & ~(uintptr_t)255);
}

extern "C" void kernel_launch(void* const* d_in, const int* in_sizes, int n_in,
                              void* d_out, int out_size, void* d_ws, size_t ws_size,
                              hipStream_t stream) {
  const int*   x_ids = (const int*)d_in[0];
  const int*   edge  = (const int*)d_in[1];
  const int*   batch = (const int*)d_in[2];
  const float* emb   = (const float*)d_in[3];
  const float* W1    = (const float*)d_in[4];
  const float* b1    = (const float*)d_in[5];
  const float* W2    = (const float*)d_in[6];
  const float* b2    = (const float*)d_in[7];
  const float* W3    = (const float*)d_in[8];
  const float* b3    = (const float*)d_in[9];
  const float* Wf1   = (const float*)d_in[10];
  const float* bf1   = (const float*)d_in[11];
  const float* Wf2   = (const float*)d_in[12];
  const float* bf2   = (const float*)d_in[13];
  float* out = (float*)d_out;

  const int N = in_sizes[0];
  const int E = in_sizes[1] / 2;
  const int G = out_size;
  const int* e_src = edge;
  const int* e_dst = edge + E;

  const size_t EPAD = (size_t)E + 8 * (size_t)(N + 1) + 128;  // padded csr capacity (+chunk slack)

  // workspace layout (fp8 feature buffers, N+1 rows for sentinel)
  char* p = (char*)d_ws;
  u8*    bufA = (u8*)p;               p = align256(p + (size_t)(N + 1) * 64);
  u8*    bufB = (u8*)p;               p = align256(p + (size_t)(N + 1) * 64);
  u32*   csr  = (u32*)p;              p = align256(p + EPAD * 4);
  int*   rank = (int*)p;              p = align256(p + (size_t)E * 4);
  float* dsc  = (float*)p;            p = align256(p + (size_t)(N + 1) * 4);
  int*   cnt8 = (int*)p;              p = align256(p + (size_t)8 * N * 4);
  int*   offs = (int*)p;              p = align256(p + (size_t)(N + 1) * 4);
  int*   bsum = (int*)p;              p = align256(p + (size_t)1024 * 4);
  (void)ws_size; (void)n_in;

  const int nb_scan = (N + 1023) / 1024;  // 98 for N=100000 (<=128)
  dim3 blk(256);

  // CSR build
  k_init<<<dim3(512), blk, 0, stream>>>(cnt8, 8 * N, bufA + (size_t)N * 64, bufB + (size_t)N * 64);
  k_count_rank<<<dim3((E + 255) / 256), blk, 0, stream>>>(e_dst, cnt8, rank, E, N);
  k_scan1<<<dim3(nb_scan), blk, 0, stream>>>(cnt8, N, bsum);
  k_scan2<<<dim3(1), dim3(128), 0, stream>>>(bsum, nb_scan, offs + N);
  k_scan3<<<dim3(nb_scan), blk, 0, stream>>>(cnt8, N, bsum, offs, dsc, csr);

  // fused: layer-1 GEMM (blocks [0,mmb)) overlapped with CSR scatter (rest)
  const int mmb = (N + 255) / 256;
  const int scb = (E + 255) / 256;
  k_mm1_scatter<<<dim3(mmb + scb), blk, 0, stream>>>(
      x_ids, emb, W1, bufA, N, mmb,
      e_src, e_dst, rank, cnt8, dsc, csr, E);

  // fused conv+next-GEMM chain: ONE group per wave, exact grid
  const int ngroups = (N + 3) / 4;
  const int agg_grid = (ngroups + 3) / 4;
  k_agg<false><<<dim3(agg_grid), blk, 0, stream>>>(bufA, csr, offs, dsc, b1, W2, bufB, N);
  k_agg<false><<<dim3(agg_grid), blk, 0, stream>>>(bufB, csr, offs, dsc, b2, W3, bufA, N);
  k_agg<true><<<dim3(agg_grid), blk, 0, stream>>>(bufA, csr, offs, dsc, b3, nullptr, bufB, N);

  // pool + MLP head
  k_pool<<<dim3(G), blk, 0, stream>>>(bufB, batch, N, Wf1, bf1, Wf2, bf2, out);
}

// Round 17
// 339.201 us; speedup vs baseline: 1.1788x; 1.0521x over previous
//
#include <hip/hip_runtime.h>
#include <hip/hip_bf16.h>
#include <hip/hip_fp8.h>

// GCN, fp8(e4m3) PRE-MULTIPLIED node features z[v] = h[v]*dinv[v]*S, fp32 accum.
//  Agg: one 4-node group per wave; 128-edge staging (ce_lo/ce_hi), runtime
//  batch count nb with guarded static 16-batch unroll (no chunk-quantization
//  waste), 4-deep prefetch. Fused next-W GEMM via readlane.
//  CSR build: 8 XCD-pinned counters, rank capture, atomic-free scatter fused
//  with layer-1 GEMM. k_pool: mean pool + MLP + sigmoid.

typedef unsigned char u8;
typedef unsigned short u16;
typedef unsigned int u32;

#define FSCALE 256.0f
#define SINV (1.0f / 256.0f)
#define S2 65536.0f

__device__ __forceinline__ float fp8d(u32 b) {
#if __has_builtin(__builtin_amdgcn_cvt_f32_fp8)
  return __builtin_amdgcn_cvt_f32_fp8((int)b, 0);
#else
  __hip_fp8_e4m3 t; t.__x = (__hip_fp8_storage_t)b; return (float)t;
#endif
}
__device__ __forceinline__ u32 fp8e1(float f) {
#if __has_builtin(__builtin_amdgcn_cvt_pk_fp8_f32)
  return (u32)__builtin_amdgcn_cvt_pk_fp8_f32(f, 0.f, 0, false) & 0xffu;
#else
  __hip_fp8_e4m3 t(f); return (u32)t.__x;
#endif
}
__device__ __forceinline__ u32 fp8e4(float f0, float f1, float f2, float f3) {
#if __has_builtin(__builtin_amdgcn_cvt_pk_fp8_f32)
  int r = 0;
  r = __builtin_amdgcn_cvt_pk_fp8_f32(f0, f1, r, false);
  r = __builtin_amdgcn_cvt_pk_fp8_f32(f2, f3, r, true);
  return (u32)r;
#else
  __hip_fp8_e4m3 a(f0), b(f1), c(f2), d(f3);
  return (u32)a.__x | ((u32)b.__x << 8) | ((u32)c.__x << 16) | ((u32)d.__x << 24);
#endif
}

// ---------------- init: zero partition counters + sentinel feature rows ----------------
__global__ __launch_bounds__(256) void k_init(int* __restrict__ cnt8, int n8,
                                              u8* __restrict__ rowA, u8* __restrict__ rowB) {
  int i = blockIdx.x * blockDim.x + threadIdx.x;
  int stride = gridDim.x * blockDim.x;
  for (; i < n8; i += stride) cnt8[i] = 0;
  if (blockIdx.x == 0 && threadIdx.x < 64) {
    rowA[threadIdx.x] = 0;
    rowB[threadIdx.x] = 0;
  }
}

// count in-degree into partition (blockIdx&7) counter; rank = atomic return.
__global__ __launch_bounds__(256) void k_count_rank(const int* __restrict__ dst, int* __restrict__ cnt8,
                                                    int* __restrict__ rank, int e_count, int n) {
  int e = blockIdx.x * blockDim.x + threadIdx.x;
  if (e < e_count) {
    int p = blockIdx.x & 7;
    rank[e] = atomicAdd(&cnt8[p * n + dst[e]], 1);
  }
}

// scan over PADDED totals ((sum8+7)&~7)
__global__ __launch_bounds__(256) void k_scan1(const int* __restrict__ cnt8, int n, int* __restrict__ bsum) {
  __shared__ int s[256];
  int b = blockIdx.x, t = threadIdx.x;
  int base = b * 1024;
  int sum = 0;
  #pragma unroll
  for (int i = 0; i < 4; ++i) {
    int idx = base + t + i * 256;
    if (idx < n) {
      int c = 0;
      #pragma unroll
      for (int q = 0; q < 8; ++q) c += cnt8[q * n + idx];
      sum += (c + 7) & ~7;
    }
  }
  s[t] = sum; __syncthreads();
  for (int off = 128; off > 0; off >>= 1) {
    if (t < off) s[t] += s[t + off];
    __syncthreads();
  }
  if (t == 0) bsum[b] = s[0];
}

__global__ __launch_bounds__(128) void k_scan2(int* __restrict__ bsum, int nb, int* __restrict__ total_out) {
  __shared__ int sh[128];
  int t = threadIdx.x;
  sh[t] = (t < nb) ? bsum[t] : 0;
  __syncthreads();
  for (int off = 1; off < 128; off <<= 1) {
    int x = sh[t];
    int y = (t >= off) ? sh[t - off] : 0;
    __syncthreads();
    sh[t] = x + y;
    __syncthreads();
  }
  if (t < nb) bsum[t] = (t == 0) ? 0 : sh[t - 1];
  if (t == 0) *total_out = sh[127];
}

// scan3: padded offsets, dsc = dinv/S, per-partition bases (in-place), pads.
__global__ __launch_bounds__(256) void k_scan3(int* __restrict__ cnt8, int n,
                                               const int* __restrict__ bsum_ex, int* __restrict__ offsets,
                                               float* __restrict__ dsc, u32* __restrict__ csr) {
  __shared__ int sh[256];
  int b = blockIdx.x, t = threadIdx.x;
  int base = b * 1024 + t * 4;
  int cq[4][8];
  int c[4], v[4];
  #pragma unroll
  for (int i = 0; i < 4; ++i) {
    c[i] = 0;
    #pragma unroll
    for (int q = 0; q < 8; ++q) {
      int x = (base + i < n) ? cnt8[q * n + base + i] : 0;
      cq[i][q] = x;
      c[i] += x;
    }
    v[i] = (c[i] + 7) & ~7;
    if (base + i < n) dsc[base + i] = rsqrtf((float)c[i] + 1.0f) * SINV;
  }
  sh[t] = v[0] + v[1] + v[2] + v[3];
  __syncthreads();
  for (int off = 1; off < 256; off <<= 1) {
    int x = sh[t];
    int y = (t >= off) ? sh[t - off] : 0;
    __syncthreads();
    sh[t] = x + y;
    __syncthreads();
  }
  int run = bsum_ex[b] + ((t == 0) ? 0 : sh[t - 1]);
  #pragma unroll
  for (int i = 0; i < 4; ++i) {
    if (base + i < n) {
      offsets[base + i] = run;
      int pb = run;
      #pragma unroll
      for (int q = 0; q < 8; ++q) {
        cnt8[q * n + base + i] = pb;  // partition base (in-place)
        pb += cq[i][q];
      }
      for (int j = run + c[i]; j < run + v[i]; ++j) csr[j] = (u32)n;  // sentinel pads
      run += v[i];
    }
  }
  if (b == 0 && t == 0) dsc[n] = 0.f;
}

// ---------------- fused layer-1 GEMM (blocks [0,mmb)) + scatter (rest) ----------------
// mm1 stores z1 = (emb@W1) * dinv[r] * S  (= acc * dsc[r] * S^2).
__global__ __launch_bounds__(256, 4) void k_mm1_scatter(
    const int* __restrict__ ids, const float* __restrict__ emb,
    const float* __restrict__ W1, u8* __restrict__ out, int n, int mmb,
    const int* __restrict__ src, const int* __restrict__ dst,
    const int* __restrict__ rank, const int* __restrict__ pbase,
    const float* __restrict__ dsc, u32* __restrict__ csr, int e_count) {
  if ((int)blockIdx.x >= mmb) {
    int eb = blockIdx.x - mmb;
    int e = eb * 256 + threadIdx.x;
    if (e < e_count) {
      int p = eb & 7;  // matches k_count_rank's blockIdx&7
      int d = dst[e];
      int pos = pbase[p * n + d] + rank[e];
      __builtin_nontemporal_store((u32)src[e], &csr[pos]);
    }
    return;
  }

  const int lane = threadIdx.x & 63;
  const int w = threadIdx.x >> 6;
  const int r = blockIdx.x * 256 + w * 64 + lane;
  const int rc = (r < n) ? r : (n - 1);
  const int rid = ids[rc];
  const float zs = dsc[rc] * S2;  // dinv[r] * S
  const float4* __restrict__ xrow = reinterpret_cast<const float4*>(emb + (size_t)rid * 128);

  float acc[64];
  #pragma unroll
  for (int j = 0; j < 64; ++j) acc[j] = 0.f;

  #pragma unroll 1
  for (int s = 0; s < 4; ++s) {
    float4 xb[8];
    #pragma unroll
    for (int i = 0; i < 8; ++i) xb[i] = xrow[s * 8 + i];
    const float* __restrict__ wbase = W1 + (size_t)(s * 32) * 64;
    #pragma unroll
    for (int i = 0; i < 8; ++i) {
      const float* __restrict__ w0 = wbase + (i * 4) * 64;
      #pragma unroll
      for (int j = 0; j < 64; ++j) {
        acc[j] = fmaf(xb[i].x, w0[j], acc[j]);
        acc[j] = fmaf(xb[i].y, w0[64 + j], acc[j]);
        acc[j] = fmaf(xb[i].z, w0[128 + j], acc[j]);
        acc[j] = fmaf(xb[i].w, w0[192 + j], acc[j]);
      }
    }
  }

  if (r < n) {
    u8* op = out + (size_t)r * 64;
    #pragma unroll
    for (int q = 0; q < 4; ++q) {
      uint4 pk;
      pk.x = fp8e4(acc[q * 16 + 0] * zs, acc[q * 16 + 1] * zs,
                   acc[q * 16 + 2] * zs, acc[q * 16 + 3] * zs);
      pk.y = fp8e4(acc[q * 16 + 4] * zs, acc[q * 16 + 5] * zs,
                   acc[q * 16 + 6] * zs, acc[q * 16 + 7] * zs);
      pk.z = fp8e4(acc[q * 16 + 8] * zs, acc[q * 16 + 9] * zs,
                   acc[q * 16 + 10] * zs, acc[q * 16 + 11] * zs);
      pk.w = fp8e4(acc[q * 16 + 12] * zs, acc[q * 16 + 13] * zs,
                   acc[q * 16 + 14] * zs, acc[q * 16 + 15] * zs);
      *reinterpret_cast<uint4*>(op + q * 16) = pk;
    }
  }
}

// ---------------- fused aggregation + next-layer GEMM ----------------
// z = h*dinv*S (fp8). tmp = sum fp8d(z[src]); acc += tmp * dsc[dst].
// One 4-node group per wave. 128-edge staging (ce_lo/ce_hi); nb = cnt/8 real
// batches; guarded static 16-batch unroll with 4-deep prefetch. Batches beyond
// nb are SKIPPED (execz) instead of processed as sentinel work.

#define G8(dstreg, CE, OFF)                                                  \
  _Pragma("unroll")                                                          \
  for (int t_ = 0; t_ < 8; ++t_) {                                           \
    int sb_ = __builtin_amdgcn_readlane((int)CE, (OFF) + t_);                \
    dstreg[t_] = (u32)z[(size_t)sb_ * 64 + lane];                            \
  }

#define C8(srcreg, OFF)                                                      \
  {                                                                          \
    float tmp_ = 0.f;                                                        \
    _Pragma("unroll")                                                        \
    for (int t_ = 0; t_ < 8; ++t_) tmp_ += fp8d(srcreg[t_]);                 \
    const int ep_ = e + (OFF);                                               \
    if (ep_ < b1) acc0 = fmaf(tmp_, d0, acc0);                               \
    else if (ep_ < b2) acc1 = fmaf(tmp_, d1, acc1);                          \
    else if (ep_ < b3) acc2 = fmaf(tmp_, d2, acc2);                          \
    else acc3 = fmaf(tmp_, d3, acc3);                                        \
  }

template <bool FINAL>
__global__ __launch_bounds__(256, 4) void k_agg(const u8* __restrict__ z, const u32* __restrict__ csr,
                                                const int* __restrict__ offs, const float* __restrict__ dsc,
                                                const float* __restrict__ bias, const float* __restrict__ Wn,
                                                u8* __restrict__ out, int n) {
  const int lane = threadIdx.x & 63;
  const int w = threadIdx.x >> 6;
  const int ngroups = (n + 3) >> 2;
  const int grp = blockIdx.x * 4 + w;  // exactly one group per wave
  if (grp >= ngroups) return;
  const float bl = bias[lane];

  const int v0 = grp * 4;
  const int c1 = (v0 + 1 < n) ? v0 + 1 : n;
  const int c2 = (v0 + 2 < n) ? v0 + 2 : n;
  const int c3 = (v0 + 3 < n) ? v0 + 3 : n;
  const int b0 = offs[v0], b1 = offs[c1], b2 = offs[c2], b3 = offs[c3];
  const int b4 = offs[(v0 + 4 < n) ? v0 + 4 : n];

  const float d0 = dsc[v0];
  const float d1 = dsc[(c1 < n) ? c1 : v0];
  const float d2 = dsc[(c2 < n) ? c2 : v0];
  const float d3 = dsc[(c3 < n) ? c3 : v0];
  float acc0 = fmaf(fp8d(z[(size_t)v0 * 64 + lane]), d0, bl);
  float acc1 = (c1 < n) ? fmaf(fp8d(z[(size_t)c1 * 64 + lane]), d1, bl) : 0.f;
  float acc2 = (c2 < n) ? fmaf(fp8d(z[(size_t)c2 * 64 + lane]), d2, bl) : 0.f;
  float acc3 = (c3 < n) ? fmaf(fp8d(z[(size_t)c3 * 64 + lane]), d3, bl) : 0.f;

  int e = b0;
  while (e < b4) {
    int cnt = b4 - e;
    cnt = (cnt < 128) ? cnt : 128;
    const int nb = cnt >> 3;  // 1..16 real batches (cnt is a multiple of 8)
    u32 celo = (u32)n, cehi = (u32)n;
    if (lane < cnt) celo = csr[e + lane];
    if (64 + lane < cnt) cehi = csr[e + 64 + lane];

    u32 gA[8], gB[8], gC[8], gD[8];
    // prologue: up to 4 batches in flight
    G8(gA, celo, 0)
    if (nb > 1) G8(gB, celo, 8)
    if (nb > 2) G8(gC, celo, 16)
    if (nb > 3) G8(gD, celo, 24)
    // guarded static unroll: consume batch k, prefetch batch k+4
    { C8(gA, 0)               if (nb > 4)  G8(gA, celo, 32) }
    if (nb > 1)  { C8(gB, 8)   if (nb > 5)  G8(gB, celo, 40) }
    if (nb > 2)  { C8(gC, 16)  if (nb > 6)  G8(gC, celo, 48) }
    if (nb > 3)  { C8(gD, 24)  if (nb > 7)  G8(gD, celo, 56) }
    if (nb > 4)  { C8(gA, 32)  if (nb > 8)  G8(gA, cehi, 0)  }
    if (nb > 5)  { C8(gB, 40)  if (nb > 9)  G8(gB, cehi, 8)  }
    if (nb > 6)  { C8(gC, 48)  if (nb > 10) G8(gC, cehi, 16) }
    if (nb > 7)  { C8(gD, 56)  if (nb > 11) G8(gD, cehi, 24) }
    if (nb > 8)  { C8(gA, 64)  if (nb > 12) G8(gA, cehi, 32) }
    if (nb > 9)  { C8(gB, 72)  if (nb > 13) G8(gB, cehi, 40) }
    if (nb > 10) { C8(gC, 80)  if (nb > 14) G8(gC, cehi, 48) }
    if (nb > 11) { C8(gD, 88)  if (nb > 15) G8(gD, cehi, 56) }
    if (nb > 12) { C8(gA, 96) }
    if (nb > 13) { C8(gB, 104) }
    if (nb > 14) { C8(gC, 112) }
    if (nb > 15) { C8(gD, 120) }
    e += cnt;
  }

  float h0 = fmaxf(acc0, 0.f), h1 = fmaxf(acc1, 0.f);
  float h2 = fmaxf(acc2, 0.f), h3 = fmaxf(acc3, 0.f);
  if constexpr (FINAL) {
    out[(size_t)v0 * 64 + lane] = (u8)fp8e1(h0 * FSCALE);
    if (c1 < n) out[(size_t)c1 * 64 + lane] = (u8)fp8e1(h1 * FSCALE);
    if (c2 < n) out[(size_t)c2 * 64 + lane] = (u8)fp8e1(h2 * FSCALE);
    if (c3 < n) out[(size_t)c3 * 64 + lane] = (u8)fp8e1(h3 * FSCALE);
  } else {
    const int hb0 = __float_as_int(h0), hb1 = __float_as_int(h1);
    const int hb2 = __float_as_int(h2), hb3 = __float_as_int(h3);
    float o0 = 0.f, o1 = 0.f, o2 = 0.f, o3 = 0.f;
    #pragma unroll
    for (int k = 0; k < 64; ++k) {
      float wk = Wn[k * 64 + lane];
      o0 = fmaf(__int_as_float(__builtin_amdgcn_readlane(hb0, k)), wk, o0);
      o1 = fmaf(__int_as_float(__builtin_amdgcn_readlane(hb1, k)), wk, o1);
      o2 = fmaf(__int_as_float(__builtin_amdgcn_readlane(hb2, k)), wk, o2);
      o3 = fmaf(__int_as_float(__builtin_amdgcn_readlane(hb3, k)), wk, o3);
    }
    // store z' = o * dinv * S = o * dsc * S^2
    out[(size_t)v0 * 64 + lane] = (u8)fp8e1(o0 * d0 * S2);
    if (c1 < n) out[(size_t)c1 * 64 + lane] = (u8)fp8e1(o1 * d1 * S2);
    if (c2 < n) out[(size_t)c2 * 64 + lane] = (u8)fp8e1(o2 * d2 * S2);
    if (c3 < n) out[(size_t)c3 * 64 + lane] = (u8)fp8e1(o3 * d3 * S2);
  }
}

// ---------------- pooling + MLP head + sigmoid ----------------
__global__ __launch_bounds__(256) void k_pool(const u8* __restrict__ x, const int* __restrict__ batch, int n,
                                              const float* __restrict__ Wf1, const float* __restrict__ bf1,
                                              const float* __restrict__ Wf2, const float* __restrict__ bf2,
                                              float* __restrict__ out) {
  int g = blockIdx.x;
  int tid = threadIdx.x, lane = tid & 63, w = tid >> 6;
  int a = 0, b = n;
  while (a < b) { int m = (a + b) >> 1; if (batch[m] < g) a = m + 1; else b = m; }
  int lo = a;
  b = n;
  while (a < b) { int m = (a + b) >> 1; if (batch[m] < g + 1) a = m + 1; else b = m; }
  int hi = a;

  float acc = 0.f;
  for (int r = lo + w; r < hi; r += 4) acc += fp8d(x[(size_t)r * 64 + lane]);
  __shared__ float red[4][64];
  __shared__ float mean[64];
  red[w][lane] = acc;
  __syncthreads();
  if (w == 0) {
    float s = red[0][lane] + red[1][lane] + red[2][lane] + red[3][lane];
    mean[lane] = s / (fmaxf((float)(hi - lo), 1.0f) * FSCALE);
  }
  __syncthreads();
  if (w == 0) {
    float h = bf1[lane];
    #pragma unroll
    for (int k = 0; k < 64; ++k) h = fmaf(mean[k], Wf1[k * 64 + lane], h);
    h = fmaxf(h, 0.f);
    float vv = h * Wf2[lane];
    for (int off = 32; off > 0; off >>= 1) vv += __shfl_down(vv, off, 64);
    if (lane == 0) out[g] = 1.0f / (1.0f + expf(-(vv + bf2[0])));
  }
}

static inline char* align256(char* p) {
  return (char*)(((uintptr_t)p + 255) & ~(uintptr_t)255);
}

extern "C" void kernel_launch(void* const* d_in, const int* in_sizes, int n_in,
                              void* d_out, int out_size, void* d_ws, size_t ws_size,
                              hipStream_t stream) {
  const int*   x_ids = (const int*)d_in[0];
  const int*   edge  = (const int*)d_in[1];
  const int*   batch = (const int*)d_in[2];
  const float* emb   = (const float*)d_in[3];
  const float* W1    = (const float*)d_in[4];
  const float* b1    = (const float*)d_in[5];
  const float* W2    = (const float*)d_in[6];
  const float* b2    = (const float*)d_in[7];
  const float* W3    = (const float*)d_in[8];
  const float* b3    = (const float*)d_in[9];
  const float* Wf1   = (const float*)d_in[10];
  const float* bf1   = (const float*)d_in[11];
  const float* Wf2   = (const float*)d_in[12];
  const float* bf2   = (const float*)d_in[13];
  float* out = (float*)d_out;

  const int N = in_sizes[0];
  const int E = in_sizes[1] / 2;
  const int G = out_size;
  const int* e_src = edge;
  const int* e_dst = edge + E;

  const size_t EPAD = (size_t)E + 8 * (size_t)(N + 1) + 256;  // padded csr capacity (+staging slack)

  // workspace layout (fp8 feature buffers, N+1 rows for sentinel)
  char* p = (char*)d_ws;
  u8*    bufA = (u8*)p;               p = align256(p + (size_t)(N + 1) * 64);
  u8*    bufB = (u8*)p;               p = align256(p + (size_t)(N + 1) * 64);
  u32*   csr  = (u32*)p;              p = align256(p + EPAD * 4);
  int*   rank = (int*)p;              p = align256(p + (size_t)E * 4);
  float* dsc  = (float*)p;            p = align256(p + (size_t)(N + 1) * 4);
  int*   cnt8 = (int*)p;              p = align256(p + (size_t)8 * N * 4);
  int*   offs = (int*)p;              p = align256(p + (size_t)(N + 1) * 4);
  int*   bsum = (int*)p;              p = align256(p + (size_t)1024 * 4);
  (void)ws_size; (void)n_in;

  const int nb_scan = (N + 1023) / 1024;  // 98 for N=100000 (<=128)
  dim3 blk(256);

  // CSR build
  k_init<<<dim3(512), blk, 0, stream>>>(cnt8, 8 * N, bufA + (size_t)N * 64, bufB + (size_t)N * 64);
  k_count_rank<<<dim3((E + 255) / 256), blk, 0, stream>>>(e_dst, cnt8, rank, E, N);
  k_scan1<<<dim3(nb_scan), blk, 0, stream>>>(cnt8, N, bsum);
  k_scan2<<<dim3(1), dim3(128), 0, stream>>>(bsum, nb_scan, offs + N);
  k_scan3<<<dim3(nb_scan), blk, 0, stream>>>(cnt8, N, bsum, offs, dsc, csr);

  // fused: layer-1 GEMM (blocks [0,mmb)) overlapped with CSR scatter (rest)
  const int mmb = (N + 255) / 256;
  const int scb = (E + 255) / 256;
  k_mm1_scatter<<<dim3(mmb + scb), blk, 0, stream>>>(
      x_ids, emb, W1, bufA, N, mmb,
      e_src, e_dst, rank, cnt8, dsc, csr, E);

  // fused conv+next-GEMM chain: ONE group per wave, exact grid
  const int ngroups = (N + 3) / 4;
  const int agg_grid = (ngroups + 3) / 4;
  k_agg<false><<<dim3(agg_grid), blk, 0, stream>>>(bufA, csr, offs, dsc, b1, W2, bufB, N);
  k_agg<false><<<dim3(agg_grid), blk, 0, stream>>>(bufB, csr, offs, dsc, b2, W3, bufA, N);
  k_agg<true><<<dim3(agg_grid), blk, 0, stream>>>(bufA, csr, offs, dsc, b3, nullptr, bufB, N);

  // pool + MLP head
  k_pool<<<dim3(G), blk, 0, stream>>>(bufB, batch, N, Wf1, bf1, Wf2, bf2, out);
}